// Round 3
// baseline (4830.717 us; speedup 1.0000x reference)
//
#include <hip/hip_runtime.h>
#include <math.h>

#define BB 32
#define CC 64
#define LL 8192
#define WIN 32
#define HOP 8
#define NW 1021          // (8192-32)/8 + 1
#define NT 1022          // NW + 1
#define NBINS 4096       // sum of Ls/2 over segments == LL/2
#define SEGSTRIDE 1024   // max segments per batch (each >= 8 samples)
#define OFFSTRIDE 1025
#define MAXTOK 2048
#define ANCH 16
#define TWO_PI 6.283185307179586476925286766559
#define PRUNE_MARGIN 1e-6

// ---------------- K1: channel mean (sequential f32 accumulation, matches numpy axis-0 reduce)
__global__ void k_agg(const float* __restrict__ x, float* __restrict__ agg) {
  int idx = blockIdx.x * blockDim.x + threadIdx.x;
  if (idx >= BB * LL) return;
  int b = idx / LL, l = idx - b * LL;
  const float* xp = x + (size_t)b * CC * LL + l;
  float acc = 0.0f;
  for (int c = 0; c < CC; ++c) acc += xp[(size_t)c * LL];
  agg[idx] = acc / 64.0f;
}

// ---------------- K2: per-window spectral features (f64 DFT len 32, bins 1..16), f32 cast
__global__ void k_winfeat(const float* __restrict__ agg, float* __restrict__ feat) {
  __shared__ double ct[32], st[32];
  int b = blockIdx.x;
  int w = blockIdx.y * blockDim.x + threadIdx.x;
  if (threadIdx.x < 32) {
    double ang = -TWO_PI * (double)threadIdx.x / 32.0;
    sincos(ang, &st[threadIdx.x], &ct[threadIdx.x]);
  }
  __syncthreads();
  if (w >= NW) return;
  const float* a = agg + b * LL + w * HOP;
  double p[17];
  for (int k = 1; k <= 16; ++k) {
    double re = 0.0, im = 0.0;
    int m = 0;
    for (int n = 0; n < 32; ++n) {
      double av = (double)a[n];
      re += av * ct[m];
      im += av * st[m];
      m = (m + k) & 31;
    }
    p[k] = re * re + im * im;
  }
  // numpy pairwise (16 elems): r[j] = x[j] + x[j+8]; ((r0+r1)+(r2+r3))+((r4+r5)+(r6+r7))
  double r[8];
  for (int j = 0; j < 8; ++j) r[j] = p[1 + j] + p[9 + j];
  double total = ((r[0] + r[1]) + (r[2] + r[3])) + ((r[4] + r[5]) + (r[6] + r[7]));
  double denom = total + 1e-12;
  double probs[17];
  for (int k = 1; k <= 16; ++k) probs[k] = p[k] / denom;
  for (int j = 0; j < 8; ++j)
    r[j] = probs[1 + j] * ((double)(1 + j) / 32.0) + probs[9 + j] * ((double)(9 + j) / 32.0);
  double centroid = ((r[0] + r[1]) + (r[2] + r[3])) + ((r[4] + r[5]) + (r[6] + r[7]));
  for (int j = 0; j < 8; ++j) {
    double f0 = (double)(1 + j) / 32.0 - centroid;
    double f1 = (double)(9 + j) / 32.0 - centroid;
    r[j] = probs[1 + j] * (f0 * f0) + probs[9 + j] * (f1 * f1);
  }
  double var = ((r[0] + r[1]) + (r[2] + r[3])) + ((r[4] + r[5]) + (r[6] + r[7]));
  double spread = sqrt(fmax(var, 0.0));
  size_t fo = ((size_t)b * 1024 + w) * 3;
  feat[fo + 0] = (float)centroid;
  feat[fo + 1] = (float)(2.0 * spread);
  feat[fo + 2] = (float)log1p(total / 32.0);
}

// ---------------- K3: PELT DP changepoints, single-wave + margin-pruned candidate set
// LDS budget ~51.1 KB (must stay < 64 KB — 84 KB variant failed to launch).
// Pruning: SSE cost is superadditive, so F[j]+cost(j,t) > F[t]+margin implies j is
// worse than the running minimum by > margin at every future t' (margin=1e-6 >> 1e-13
// FP noise) -> can never flip an argmin or create a tie. Candidate order stays
// ascending, preserving numpy's first-occurrence argmin.
// cs2 per-dim array is folded to q[i]=sum_d cs2[i][d]; per-dim cumsums stay
// bit-exact sequential, only the 3-term dim-sum association changes (~1e-13 abs).
__global__ void __launch_bounds__(64)
k_dp(const float* __restrict__ feat,
     int* __restrict__ seg_s, int* __restrict__ seg_e,
     int* __restrict__ nsegp, int* __restrict__ segoff, int* __restrict__ binseg) {
  int b = blockIdx.x, lane = threadIdx.x;
  __shared__ double cs[NT][3];     // 24528 B  per-dim cumsum
  __shared__ double q[NT];         //  8176 B  sum-over-dims cumsum of squares
  __shared__ double G[NT];         //  8176 B  F[j] - q[j]
  __shared__ short parent[NT];     //  2044 B
  __shared__ int cj[NT];           //  4088 B  candidate list (ascending j)
  __shared__ int soff[OFFSTRIDE];  //  4100 B
  __shared__ int ns_sh;            //     4 B   => ~51.1 KB total

  if (lane == 0) {
    cs[0][0] = 0.0; cs[0][1] = 0.0; cs[0][2] = 0.0;
    q[0] = 0.0; G[0] = 0.0; cj[0] = 0;
  }
  if (lane < 6) {  // lanes 0-2: feature cumsum dims; lanes 3-5: squared cumsum dims
    int d = lane % 3; bool sq = lane >= 3;
    double acc = 0.0;
    for (int i = 0; i < NW; ++i) {
      double v = (double)feat[((size_t)b * 1024 + i) * 3 + d];
      acc += sq ? v * v : v;
      if (!sq) cs[i + 1][d] = acc;
      double a4 = __shfl(acc, 4);       // lanes 3,4,5 active here
      double a5 = __shfl(acc, 5);
      if (lane == 3) q[i + 1] = (acc + a4) + a5;
    }
  }
  __syncthreads();

  int nc = 1;
  for (int t = 1; t <= NW; ++t) {
    double ct0 = cs[t][0], ct1 = cs[t][1], ct2 = cs[t][2];
    double Qt3 = q[t] + 3.0;     // fold +penalty
    double bv = INFINITY; int bj = 0x7fffffff;
    if (nc <= 64) {
      // ---- fast path: one candidate per lane, val stays in a register
      bool valid = lane < nc;
      int j = valid ? cj[lane] : 0;
      double d0 = ct0 - cs[j][0], d1 = ct1 - cs[j][1], d2 = ct2 - cs[j][2];
      double dd = (d0 * d0 + d1 * d1) + d2 * d2;
      double val = (G[j] + Qt3) - dd / (double)(t - j);
      if (valid) { bv = val; bj = j; }
      for (int m = 32; m; m >>= 1) {
        double ov = __shfl_xor(bv, m);
        int oj = __shfl_xor(bj, m);
        if (ov < bv || (ov == bv && oj < bj)) { bv = ov; bj = oj; }
      }
      double thr = bv + 3.0 + PRUNE_MARGIN;
      bool keep = valid && (val <= thr);
      unsigned long long mk = __ballot(keep);
      int pos = (int)__popcll(mk & ((1ULL << lane) - 1ULL));
      if (keep) cj[pos] = j;      // wave-wide: the cj[lane] read above precedes this
      int newnc = (int)__popcll(mk);
      if (lane == 0) { parent[t] = (short)bj; G[t] = bv - q[t]; cj[newnc] = t; }
      nc = newnc + 1;
    } else {
      // ---- general path: chunked scan, recompute cost in prune pass
      int chunks = (nc + 63) >> 6;
      for (int ck = 0; ck < chunks; ++ck) {
        int idx = (ck << 6) + lane;
        bool valid = idx < nc;
        int j = valid ? cj[idx] : 0;
        double d0 = ct0 - cs[j][0], d1 = ct1 - cs[j][1], d2 = ct2 - cs[j][2];
        double dd = (d0 * d0 + d1 * d1) + d2 * d2;
        double val = (G[j] + Qt3) - dd / (double)(t - j);
        // within-lane candidates ascend in j, strict < keeps first occurrence
        if (valid && val < bv) { bv = val; bj = j; }
      }
      for (int m = 32; m; m >>= 1) {
        double ov = __shfl_xor(bv, m);
        int oj = __shfl_xor(bj, m);
        if (ov < bv || (ov == bv && oj < bj)) { bv = ov; bj = oj; }
      }
      double thr = bv + 3.0 + PRUNE_MARGIN;
      int newnc = 0;
      for (int ck = 0; ck < chunks; ++ck) {
        int idx = (ck << 6) + lane;
        bool valid = idx < nc;
        int j = valid ? cj[idx] : 0;            // read precedes any write this chunk
        double d0 = ct0 - cs[j][0], d1 = ct1 - cs[j][1], d2 = ct2 - cs[j][2];
        double dd = (d0 * d0 + d1 * d1) + d2 * d2;
        double val = (G[j] + Qt3) - dd / (double)(t - j);
        bool keep = valid && (val <= thr);
        unsigned long long mk = __ballot(keep);
        int pos = newnc + (int)__popcll(mk & ((1ULL << lane) - 1ULL));
        if (keep) cj[pos] = j;                  // pos <= idx, later chunks read higher idx
        newnc += (int)__popcll(mk);
      }
      if (lane == 0) { parent[t] = (short)bj; G[t] = bv - q[t]; cj[newnc] = t; }
      nc = newnc + 1;
    }
    __syncthreads();
  }

  if (lane == 0) {
    short* path = (short*)&q[0];      // reuse LDS (<= 2044 B of 8176)
    int* sb = (int*)&G[0];            // reuse LDS (<= 4100 B of 8176)
    int cnt = 0, t = NW;
    while (t > 0) { t = parent[t]; path[cnt++] = (short)t; }
    int nb = 0, prev = 0;
    sb[nb++] = 0;
    for (int i = cnt - 2; i >= 0; --i) {   // wb[1:-1] in increasing order
      int w = path[i];
      int ti = w * HOP;
      if (ti <= prev) continue;
      if (ti - prev < 8) continue;   // PATCH_MIN
      if (LL - ti < 8) continue;
      sb[nb++] = ti; prev = ti;
    }
    sb[nb++] = LL;
    int ns = nb - 1;
    ns_sh = ns;
    nsegp[b] = ns;
    int off = 0;
    for (int i = 0; i < ns; ++i) { soff[i] = off; off += (sb[i + 1] - sb[i]) >> 1; }
    soff[ns] = off;   // == NBINS
  }
  __syncthreads();
  int ns = ns_sh;
  const int* sb = (const int*)&G[0];
  for (int i = lane; i < ns; i += 64) {
    seg_s[b * SEGSTRIDE + i] = sb[i];
    seg_e[b * SEGSTRIDE + i] = sb[i + 1];
    segoff[b * OFFSTRIDE + i] = soff[i];
    int o0 = soff[i], o1 = soff[i + 1];
    for (int qq = o0; qq < o1; ++qq) binseg[b * NBINS + qq] = i;
  }
  if (lane == 0) segoff[b * OFFSTRIDE + ns] = soff[ns];
}

// ---------------- K4: per-bin segment DFT power (f64, rotation recurrence + resync)
__global__ void k_power(const float* __restrict__ agg,
                        const int* __restrict__ seg_s, const int* __restrict__ seg_e,
                        const int* __restrict__ segoff, const int* __restrict__ binseg,
                        double* __restrict__ powb) {
  int b = blockIdx.x;
  int bin = blockIdx.y * blockDim.x + threadIdx.x;   // 0..NBINS-1, all valid
  int seg = binseg[b * NBINS + bin];
  int s = seg_s[b * SEGSTRIDE + seg];
  int e = seg_e[b * SEGSTRIDE + seg];
  int Ls = e - s;
  int k = bin - segoff[b * OFFSTRIDE + seg] + 1;     // frequency index 1..Ls/2
  const float* a = agg + b * LL + s;
  double wr, wi;
  sincos(-TWO_PI * (double)k / (double)Ls, &wi, &wr);
  double cr = 1.0, ci = 0.0, re = 0.0, im = 0.0;
  for (int n = 0; n < Ls; ++n) {
    if ((n & 511) == 0 && n) {        // resync to kill recurrence drift
      int m = (k * n) % Ls;           // k*n <= 2^25, fits int
      sincos(-TWO_PI * (double)m / (double)Ls, &ci, &cr);
    }
    double av = (double)a[n];
    re = fma(av, cr, re);
    im = fma(av, ci, im);
    double nr = cr * wr - ci * wi;
    ci = fma(cr, wi, ci * wr);
    cr = nr;
  }
  powb[(size_t)b * NBINS + bin] = re * re + im * im;
}

// ---------------- K5: per-segment stats -> dom_period/bandwidth (f32), patch len, token count
__global__ void k_segstat(const double* __restrict__ powb,
                          const int* __restrict__ seg_s, const int* __restrict__ seg_e,
                          const int* __restrict__ segoff, const int* __restrict__ nsegp,
                          float* __restrict__ dpv, float* __restrict__ bwv,
                          int* __restrict__ plv, int* __restrict__ ntokv) {
  int b = blockIdx.x, sidx = blockIdx.y;
  if (sidx >= nsegp[b]) return;
  int lane = threadIdx.x;
  int s = seg_s[b * SEGSTRIDE + sidx], e = seg_e[b * SEGSTRIDE + sidx];
  int Ls = e - s;
  int K = Ls >> 1;
  const double* p = powb + (size_t)b * NBINS + segoff[b * OFFSTRIDE + sidx];
  double T = 0.0, mx = -1.0; int mi = 0x7fffffff;
  for (int j = lane; j < K; j += 64) {
    double pv = p[j];
    T += pv;
    if (pv > mx) { mx = pv; mi = j; }   // strict > keeps first occurrence per lane
  }
  for (int off = 32; off > 0; off >>= 1) {
    T += __shfl_down(T, off);
    double omx = __shfl_down(mx, off);
    int omi = __shfl_down(mi, off);
    if (omx > mx || (omx == mx && omi < mi)) { mx = omx; mi = omi; }
  }
  T = __shfl(T, 0); mi = __shfl(mi, 0);
  double denom = T + 1e-12;
  double cp = 0.0;
  for (int j = lane; j < K; j += 64) cp += p[j] * ((double)(j + 1) / (double)Ls);
  for (int off = 32; off > 0; off >>= 1) cp += __shfl_down(cp, off);
  double c = __shfl(cp, 0) / denom;
  double sp2 = 0.0;
  for (int j = lane; j < K; j += 64) {
    double d = (double)(j + 1) / (double)Ls - c;
    sp2 += p[j] * (d * d);
  }
  for (int off = 32; off > 0; off >>= 1) sp2 += __shfl_down(sp2, off);
  if (lane == 0) {
    double spread = sqrt(fmax(sp2 / denom, 0.0));
    float dp32 = (float)((double)Ls / ((double)mi + 1.0));
    float bw32 = (float)(2.0 * spread);
    double raw = (double)dp32 / (1.0 + (double)bw32);   // ALPHA=BETA=1
    int pl = (int)rint(raw * 0.5) * 2;                  // python round = half-even
    pl = pl < 8 ? 8 : (pl > 64 ? 64 : pl);
    int nf = Ls / pl;
    dpv[b * SEGSTRIDE + sidx] = dp32;
    bwv[b * SEGSTRIDE + sidx] = bw32;
    plv[b * SEGSTRIDE + sidx] = pl;
    ntokv[b * SEGSTRIDE + sidx] = nf + ((nf * pl < Ls) ? 1 : 0);
  }
}

// ---------------- K6: token plan (prefix offsets + token table) and n_tok output
__global__ void k_plan(const int* __restrict__ nsegp, const int* __restrict__ ntokv,
                       const int* __restrict__ plv,
                       const int* __restrict__ seg_s, const int* __restrict__ seg_e,
                       int* __restrict__ tok_st, int* __restrict__ tok_en,
                       int* __restrict__ tok_sg, int* __restrict__ ntok,
                       float* __restrict__ out_ntok) {
  int b = blockIdx.x, tid = threadIdx.x;
  __shared__ int toff[SEGSTRIDE];
  int ns = nsegp[b];
  if (tid == 0) {
    int acc = 0;
    for (int i = 0; i < ns; ++i) { toff[i] = acc; acc += ntokv[b * SEGSTRIDE + i]; }
    if (acc > MAXTOK) acc = MAXTOK;
    ntok[b] = acc;
    out_ntok[b] = (float)acc;
  }
  __syncthreads();
  for (int i = tid; i < ns; i += blockDim.x) {
    int base = toff[i];
    int s = seg_s[b * SEGSTRIDE + i], e = seg_e[b * SEGSTRIDE + i];
    int pl = plv[b * SEGSTRIDE + i];
    int Ls = e - s;
    int nf = Ls / pl;
    for (int t = 0; t < nf; ++t) {
      int g = base + t;
      if (g >= MAXTOK) break;
      tok_st[b * MAXTOK + g] = s + t * pl;
      tok_en[b * MAXTOK + g] = s + (t + 1) * pl;
      tok_sg[b * MAXTOK + g] = i;
    }
    if (nf * pl < Ls) {
      int g = base + nf;
      if (g < MAXTOK) {
        tok_st[b * MAXTOK + g] = s + nf * pl;
        tok_en[b * MAXTOK + g] = e;
        tok_sg[b * MAXTOK + g] = i;
      }
    }
  }
}

// ---------------- K7: metadata outputs (mask/so/eo/co/sp/rg), zero-filled beyond n_tok
__global__ void k_meta(const int* __restrict__ ntok,
                       const int* __restrict__ tok_st, const int* __restrict__ tok_en,
                       const int* __restrict__ tok_sg,
                       const float* __restrict__ dpv, const float* __restrict__ bwv,
                       const int* __restrict__ seg_s, const int* __restrict__ seg_e,
                       float* __restrict__ out, int N) {
  int idx = blockIdx.x * blockDim.x + threadIdx.x;
  if (idx >= BB * N) return;
  int b = idx / N, n = idx - b * N;
  float mask = 0, so = 0, eo = 0, co = 0, sp = 0, r0 = 0, r1 = 0, r2 = 0;
  if (n < ntok[b]) {
    int st = tok_st[b * MAXTOK + n], en = tok_en[b * MAXTOK + n], sg = tok_sg[b * MAXTOK + n];
    mask = 1.0f;
    so = (float)st; eo = (float)en;
    co = (float)(((double)st + (double)en - 1.0) * 0.5 / 8191.0);
    sp = (float)((double)(en - st) / 8192.0);
    r0 = (float)((double)dpv[b * SEGSTRIDE + sg] / 8192.0);
    r1 = bwv[b * SEGSTRIDE + sg];
    r2 = (float)((double)(seg_e[b * SEGSTRIDE + sg] - seg_s[b * SEGSTRIDE + sg]) / 8192.0);
  }
  size_t Nz = (size_t)N;
  size_t o1 = (size_t)32768 * Nz;       // after patches
  out[o1 + idx] = mask;                 // mask
  out[o1 + 32 * Nz + idx] = so;         // so
  out[o1 + 64 * Nz + idx] = eo;         // eo
  out[o1 + 96 * Nz + idx] = co;         // co
  out[o1 + 128 * Nz + idx] = sp;        // sp
  size_t o6 = o1 + 160 * Nz;            // rg
  out[o6 + (size_t)idx * 3 + 0] = r0;
  out[o6 + (size_t)idx * 3 + 1] = r1;
  out[o6 + (size_t)idx * 3 + 2] = r2;
}

// ---------------- K8: patch extraction with jax-matching linear resize to 16
__global__ void k_patches(const float* __restrict__ x,
                          const int* __restrict__ ntok,
                          const int* __restrict__ tok_st, const int* __restrict__ tok_en,
                          float* __restrict__ out, int N) {
  int blk = blockIdx.x;
  int b = blk / N, n = blk - b * N;
  size_t obase = (size_t)blk * (CC * ANCH);
  if (n >= ntok[b]) {
    for (int i = threadIdx.x; i < CC * ANCH; i += blockDim.x) out[obase + i] = 0.0f;
    return;
  }
  int st = tok_st[b * MAXTOK + n], en = tok_en[b * MAXTOK + n];
  int P = en - st;
  float scale = (float)((double)P / 16.0);
  float hi = (float)(P - 1);
  const float* xb = x + (size_t)b * CC * LL + st;
  for (int i = threadIdx.x; i < CC * ANCH; i += blockDim.x) {
    int c = i >> 4, k = i & 15;
    float pos = ((float)k + 0.5f) * scale - 0.5f;
    pos = fminf(fmaxf(pos, 0.0f), hi);
    int i0 = (int)floorf(pos);
    int i1 = min(i0 + 1, P - 1);
    float wgt = pos - (float)i0;
    const float* row = xb + (size_t)c * LL;
    out[obase + i] = row[i0] * (1.0f - wgt) + row[i1] * wgt;
  }
}

extern "C" void kernel_launch(void* const* d_in, const int* in_sizes, int n_in,
                              void* d_out, int out_size, void* d_ws, size_t ws_size,
                              hipStream_t stream) {
  const float* x = (const float*)d_in[0];
  float* out = (float*)d_out;
  // out_size = 33024*N + 32  (patches 32768N, mask/so/eo/co/sp 32N each, rg 96N, n_tok 32)
  int N = (out_size - BB) / 33024;
  if (N <= 0) return;

  char* ws = (char*)d_ws;
  size_t o = 0;
  auto A = [&](size_t bytes) { size_t r = o; o += (bytes + 255) & ~(size_t)255; return r; };
  float*  agg    = (float*) (ws + A((size_t)BB * LL * 4));
  float*  feat   = (float*) (ws + A((size_t)BB * 1024 * 3 * 4));
  int*    seg_s  = (int*)   (ws + A((size_t)BB * SEGSTRIDE * 4));
  int*    seg_e  = (int*)   (ws + A((size_t)BB * SEGSTRIDE * 4));
  int*    segoff = (int*)   (ws + A((size_t)BB * OFFSTRIDE * 4));
  int*    binseg = (int*)   (ws + A((size_t)BB * NBINS * 4));
  int*    nsegp  = (int*)   (ws + A((size_t)BB * 4));
  double* powb   = (double*)(ws + A((size_t)BB * NBINS * 8));
  float*  dpv    = (float*) (ws + A((size_t)BB * SEGSTRIDE * 4));
  float*  bwv    = (float*) (ws + A((size_t)BB * SEGSTRIDE * 4));
  int*    plv    = (int*)   (ws + A((size_t)BB * SEGSTRIDE * 4));
  int*    ntokv  = (int*)   (ws + A((size_t)BB * SEGSTRIDE * 4));
  int*    tok_st = (int*)   (ws + A((size_t)BB * MAXTOK * 4));
  int*    tok_en = (int*)   (ws + A((size_t)BB * MAXTOK * 4));
  int*    tok_sg = (int*)   (ws + A((size_t)BB * MAXTOK * 4));
  int*    ntok   = (int*)   (ws + A((size_t)BB * 4));
  (void)ws_size; (void)in_sizes; (void)n_in;

  k_agg<<<dim3((BB * LL + 255) / 256), dim3(256), 0, stream>>>(x, agg);
  k_winfeat<<<dim3(BB, (NW + 255) / 256), dim3(256), 0, stream>>>(agg, feat);
  k_dp<<<dim3(BB), dim3(64), 0, stream>>>(feat, seg_s, seg_e, nsegp, segoff, binseg);
  k_power<<<dim3(BB, NBINS / 256), dim3(256), 0, stream>>>(agg, seg_s, seg_e, segoff, binseg, powb);
  k_segstat<<<dim3(BB, SEGSTRIDE), dim3(64), 0, stream>>>(powb, seg_s, seg_e, segoff, nsegp,
                                                          dpv, bwv, plv, ntokv);
  k_plan<<<dim3(BB), dim3(256), 0, stream>>>(nsegp, ntokv, plv, seg_s, seg_e,
                                             tok_st, tok_en, tok_sg, ntok,
                                             out + (size_t)33024 * N);
  k_meta<<<dim3((BB * N + 255) / 256), dim3(256), 0, stream>>>(ntok, tok_st, tok_en, tok_sg,
                                                               dpv, bwv, seg_s, seg_e, out, N);
  k_patches<<<dim3(BB * N), dim3(256), 0, stream>>>(x, ntok, tok_st, tok_en, out, N);
}

// Round 5
// 1529.212 us; speedup vs baseline: 3.1590x; 3.1590x over previous
//
#include <hip/hip_runtime.h>
#include <math.h>

#define BB 32
#define CC 64
#define LL 8192
#define WIN 32
#define HOP 8
#define NW 1021          // (8192-32)/8 + 1
#define NT 1022          // NW + 1
#define NBINS 4096       // sum of Ls/2 over segments == LL/2
#define SEGSTRIDE 1024   // max segments per batch (each >= 8 samples)
#define OFFSTRIDE 1025
#define MAXTOK 2048
#define ANCH 16
#define TWO_PI 6.283185307179586476925286766559
#define DP_TILE 64
#define DP_WAVES 8

// ---------------- K1: channel mean (sequential f32 accumulation, matches numpy axis-0 reduce)
__global__ void k_agg(const float* __restrict__ x, float* __restrict__ agg) {
  int idx = blockIdx.x * blockDim.x + threadIdx.x;
  if (idx >= BB * LL) return;
  int b = idx / LL, l = idx - b * LL;
  const float* xp = x + (size_t)b * CC * LL + l;
  float acc = 0.0f;
  for (int c = 0; c < CC; ++c) acc += xp[(size_t)c * LL];
  agg[idx] = acc / 64.0f;
}

// ---------------- K2: per-window spectral features (f64 DFT len 32, bins 1..16), f32 cast
__global__ void k_winfeat(const float* __restrict__ agg, float* __restrict__ feat) {
  __shared__ double ct[32], st[32];
  int b = blockIdx.x;
  int w = blockIdx.y * blockDim.x + threadIdx.x;
  if (threadIdx.x < 32) {
    double ang = -TWO_PI * (double)threadIdx.x / 32.0;
    sincos(ang, &st[threadIdx.x], &ct[threadIdx.x]);
  }
  __syncthreads();
  if (w >= NW) return;
  const float* a = agg + b * LL + w * HOP;
  double p[17];
  for (int k = 1; k <= 16; ++k) {
    double re = 0.0, im = 0.0;
    int m = 0;
    for (int n = 0; n < 32; ++n) {
      double av = (double)a[n];
      re += av * ct[m];
      im += av * st[m];
      m = (m + k) & 31;
    }
    p[k] = re * re + im * im;
  }
  // numpy pairwise (16 elems): r[j] = x[j] + x[j+8]; ((r0+r1)+(r2+r3))+((r4+r5)+(r6+r7))
  double r[8];
  for (int j = 0; j < 8; ++j) r[j] = p[1 + j] + p[9 + j];
  double total = ((r[0] + r[1]) + (r[2] + r[3])) + ((r[4] + r[5]) + (r[6] + r[7]));
  double denom = total + 1e-12;
  double probs[17];
  for (int k = 1; k <= 16; ++k) probs[k] = p[k] / denom;
  for (int j = 0; j < 8; ++j)
    r[j] = probs[1 + j] * ((double)(1 + j) / 32.0) + probs[9 + j] * ((double)(9 + j) / 32.0);
  double centroid = ((r[0] + r[1]) + (r[2] + r[3])) + ((r[4] + r[5]) + (r[6] + r[7]));
  for (int j = 0; j < 8; ++j) {
    double f0 = (double)(1 + j) / 32.0 - centroid;
    double f1 = (double)(9 + j) / 32.0 - centroid;
    r[j] = probs[1 + j] * (f0 * f0) + probs[9 + j] * (f1 * f1);
  }
  double var = ((r[0] + r[1]) + (r[2] + r[3])) + ((r[4] + r[5]) + (r[6] + r[7]));
  double spread = sqrt(fmax(var, 0.0));
  size_t fo = ((size_t)b * 1024 + w) * 3;
  feat[fo + 0] = (float)centroid;
  feat[fo + 1] = (float)(2.0 * spread);
  feat[fo + 2] = (float)log1p(total / 32.0);
}

// ---------------- K3: PELT DP changepoints — tiled parallel scan (no pruning; full argmin)
// Tile of 64 t-values: phase 1 = min over prior j in [0,T0] (8 waves split j ascending,
// broadcast LDS reads, zero conflicts); phase 2 = within-tile j's resolved by wave 0
// via 63 dependent shuffle-broadcast steps. 2 barriers/tile (32 total vs 2042 in r1).
// Cost expression, association, exact f64 division, strict-< first-occurrence argmin
// and ascending-j merge order are bit-identical to the round-3 passing version.
__global__ void __launch_bounds__(512)
k_dp(const float* __restrict__ feat,
     int* __restrict__ seg_s, int* __restrict__ seg_e,
     int* __restrict__ nsegp, int* __restrict__ segoff, int* __restrict__ binseg) {
  int b = blockIdx.x, tid = threadIdx.x;
  int wv = tid >> 6, lane = tid & 63;
  __shared__ double cs[NT][3];               // 24528 B  per-dim cumsum
  __shared__ double q[NT];                   //  8176 B  sum-over-dims cumsum of squares
  __shared__ double G[NT];                   //  8176 B  F[j] - q[j]
  __shared__ short parent[NT];               //  2044 B
  __shared__ int soff[OFFSTRIDE];            //  4100 B
  __shared__ double redv[DP_WAVES][DP_TILE]; //  4096 B
  __shared__ int redi[DP_WAVES][DP_TILE];    //  2048 B
  __shared__ int ns_sh;                      //  => ~53.2 KB total (< 64 KB)

  if (tid == 0) {
    cs[0][0] = 0.0; cs[0][1] = 0.0; cs[0][2] = 0.0;
    q[0] = 0.0; G[0] = 0.0;
  }
  if (tid < 6) {  // lanes 0-2: feature cumsum dims; lanes 3-5: squared cumsum dims
    int d = tid % 3; bool sq = tid >= 3;
    double acc = 0.0;
    for (int i = 0; i < NW; ++i) {
      double v = (double)feat[((size_t)b * 1024 + i) * 3 + d];
      acc += sq ? v * v : v;
      if (!sq) cs[i + 1][d] = acc;
      double a4 = __shfl(acc, 4);       // lanes 3,4,5 active here
      double a5 = __shfl(acc, 5);
      if (tid == 3) q[i + 1] = (acc + a4) + a5;
    }
  }
  __syncthreads();

  const int ntiles = (NW + DP_TILE - 1) / DP_TILE;   // 16
  for (int g = 0; g < ntiles; ++g) {
    int T0 = g * DP_TILE;                    // prior j's: [0, T0]; t's: T0+1 .. T0+tcount
    int tcount = NW - T0; if (tcount > DP_TILE) tcount = DP_TILE;
    int t = T0 + 1 + lane;
    bool tvalid = lane < tcount;
    double ct0 = 0.0, ct1 = 0.0, ct2 = 0.0, Qt3 = 0.0;
    if (tvalid) { ct0 = cs[t][0]; ct1 = cs[t][1]; ct2 = cs[t][2]; Qt3 = q[t] + 3.0; }

    // ---- phase 1: min over j in [0, T0], waves take ascending chunks
    int njp = T0 + 1;
    int chunk = (njp + DP_WAVES - 1) / DP_WAVES;
    int j0 = wv * chunk;
    int j1 = j0 + chunk; if (j1 > njp) j1 = njp;
    double bv = INFINITY; int bj = 0x7fffffff;
    for (int j = j0; j < j1; ++j) {
      double c0 = cs[j][0], c1 = cs[j][1], c2 = cs[j][2], Gj = G[j]; // broadcast reads
      double d0 = ct0 - c0, d1 = ct1 - c1, d2 = ct2 - c2;
      double dd = (d0 * d0 + d1 * d1) + d2 * d2;
      double val = (Gj + Qt3) - dd / (double)(t - j);
      if (val < bv) { bv = val; bj = j; }   // ascending j => first occurrence
    }
    redv[wv][lane] = bv; redi[wv][lane] = bj;
    __syncthreads();

    if (wv == 0) {
      bv = redv[0][lane]; bj = redi[0][lane];
      for (int w = 1; w < DP_WAVES; ++w) {   // chunks ascend in j: tie keeps earlier wave
        double ov = redv[w][lane]; int oj = redi[w][lane];
        if (ov < bv || (ov == bv && oj < bj)) { bv = ov; bj = oj; }
      }
      // ---- phase 2: within-tile sequential resolution via shuffles
      for (int l2 = 0; l2 < tcount - 1; ++l2) {
        double Gj_self = bv - (Qt3 - 3.0);       // lane l2's F[t]-q[t] (final at step l2)
        double Gj  = __shfl(Gj_self, l2);
        double cj0 = __shfl(ct0, l2);
        double cj1 = __shfl(ct1, l2);
        double cj2 = __shfl(ct2, l2);
        if (tvalid && lane > l2) {
          double d0 = ct0 - cj0, d1 = ct1 - cj1, d2 = ct2 - cj2;
          double dd = (d0 * d0 + d1 * d1) + d2 * d2;
          double val = (Gj + Qt3) - dd / (double)(lane - l2);
          if (val < bv) { bv = val; bj = T0 + 1 + l2; }
        }
      }
      if (tvalid) { parent[t] = (short)bj; G[t] = bv - (Qt3 - 3.0); }
    }
    __syncthreads();
  }

  if (tid == 0) {
    short* path = (short*)&q[0];      // reuse LDS (<= 2044 B of 8176)
    int* sb = (int*)&G[0];            // reuse LDS (<= 4100 B of 8176)
    int cnt = 0, t = NW;
    while (t > 0) { t = parent[t]; path[cnt++] = (short)t; }
    int nb = 0, prev = 0;
    sb[nb++] = 0;
    for (int i = cnt - 2; i >= 0; --i) {   // wb[1:-1] in increasing order
      int w = path[i];
      int ti = w * HOP;
      if (ti <= prev) continue;
      if (ti - prev < 8) continue;   // PATCH_MIN
      if (LL - ti < 8) continue;
      sb[nb++] = ti; prev = ti;
    }
    sb[nb++] = LL;
    int ns = nb - 1;
    ns_sh = ns;
    nsegp[b] = ns;
    int off = 0;
    for (int i = 0; i < ns; ++i) { soff[i] = off; off += (sb[i + 1] - sb[i]) >> 1; }
    soff[ns] = off;   // == NBINS
  }
  __syncthreads();
  int ns = ns_sh;
  const int* sb = (const int*)&G[0];
  for (int i = tid; i < ns; i += 512) {
    seg_s[b * SEGSTRIDE + i] = sb[i];
    seg_e[b * SEGSTRIDE + i] = sb[i + 1];
    segoff[b * OFFSTRIDE + i] = soff[i];
    int o0 = soff[i], o1 = soff[i + 1];
    for (int qq = o0; qq < o1; ++qq) binseg[b * NBINS + qq] = i;
  }
  if (tid == 0) segoff[b * OFFSTRIDE + ns] = soff[ns];
}

// ---------------- K4: per-bin segment DFT power (f64, rotation recurrence + resync)
__global__ void k_power(const float* __restrict__ agg,
                        const int* __restrict__ seg_s, const int* __restrict__ seg_e,
                        const int* __restrict__ segoff, const int* __restrict__ binseg,
                        double* __restrict__ powb) {
  int b = blockIdx.x;
  int bin = blockIdx.y * blockDim.x + threadIdx.x;   // 0..NBINS-1, all valid
  int seg = binseg[b * NBINS + bin];
  int s = seg_s[b * SEGSTRIDE + seg];
  int e = seg_e[b * SEGSTRIDE + seg];
  int Ls = e - s;
  int k = bin - segoff[b * OFFSTRIDE + seg] + 1;     // frequency index 1..Ls/2
  const float* a = agg + b * LL + s;
  double wr, wi;
  sincos(-TWO_PI * (double)k / (double)Ls, &wi, &wr);
  double cr = 1.0, ci = 0.0, re = 0.0, im = 0.0;
  for (int n = 0; n < Ls; ++n) {
    if ((n & 511) == 0 && n) {        // resync to kill recurrence drift
      int m = (k * n) % Ls;           // k*n <= 2^25, fits int
      sincos(-TWO_PI * (double)m / (double)Ls, &ci, &cr);
    }
    double av = (double)a[n];
    re = fma(av, cr, re);
    im = fma(av, ci, im);
    double nr = cr * wr - ci * wi;
    ci = fma(cr, wi, ci * wr);
    cr = nr;
  }
  powb[(size_t)b * NBINS + bin] = re * re + im * im;
}

// ---------------- K5: per-segment stats -> dom_period/bandwidth (f32), patch len, token count
__global__ void k_segstat(const double* __restrict__ powb,
                          const int* __restrict__ seg_s, const int* __restrict__ seg_e,
                          const int* __restrict__ segoff, const int* __restrict__ nsegp,
                          float* __restrict__ dpv, float* __restrict__ bwv,
                          int* __restrict__ plv, int* __restrict__ ntokv) {
  int b = blockIdx.x, sidx = blockIdx.y;
  if (sidx >= nsegp[b]) return;
  int lane = threadIdx.x;
  int s = seg_s[b * SEGSTRIDE + sidx], e = seg_e[b * SEGSTRIDE + sidx];
  int Ls = e - s;
  int K = Ls >> 1;
  const double* p = powb + (size_t)b * NBINS + segoff[b * OFFSTRIDE + sidx];
  double T = 0.0, mx = -1.0; int mi = 0x7fffffff;
  for (int j = lane; j < K; j += 64) {
    double pv = p[j];
    T += pv;
    if (pv > mx) { mx = pv; mi = j; }   // strict > keeps first occurrence per lane
  }
  for (int off = 32; off > 0; off >>= 1) {
    T += __shfl_down(T, off);
    double omx = __shfl_down(mx, off);
    int omi = __shfl_down(mi, off);
    if (omx > mx || (omx == mx && omi < mi)) { mx = omx; mi = omi; }
  }
  T = __shfl(T, 0); mi = __shfl(mi, 0);
  double denom = T + 1e-12;
  double cp = 0.0;
  for (int j = lane; j < K; j += 64) cp += p[j] * ((double)(j + 1) / (double)Ls);
  for (int off = 32; off > 0; off >>= 1) cp += __shfl_down(cp, off);
  double c = __shfl(cp, 0) / denom;
  double sp2 = 0.0;
  for (int j = lane; j < K; j += 64) {
    double d = (double)(j + 1) / (double)Ls - c;
    sp2 += p[j] * (d * d);
  }
  for (int off = 32; off > 0; off >>= 1) sp2 += __shfl_down(sp2, off);
  if (lane == 0) {
    double spread = sqrt(fmax(sp2 / denom, 0.0));
    float dp32 = (float)((double)Ls / ((double)mi + 1.0));
    float bw32 = (float)(2.0 * spread);
    double raw = (double)dp32 / (1.0 + (double)bw32);   // ALPHA=BETA=1
    int pl = (int)rint(raw * 0.5) * 2;                  // python round = half-even
    pl = pl < 8 ? 8 : (pl > 64 ? 64 : pl);
    int nf = Ls / pl;
    dpv[b * SEGSTRIDE + sidx] = dp32;
    bwv[b * SEGSTRIDE + sidx] = bw32;
    plv[b * SEGSTRIDE + sidx] = pl;
    ntokv[b * SEGSTRIDE + sidx] = nf + ((nf * pl < Ls) ? 1 : 0);
  }
}

// ---------------- K6: token plan (prefix offsets + token table) and n_tok output
__global__ void k_plan(const int* __restrict__ nsegp, const int* __restrict__ ntokv,
                       const int* __restrict__ plv,
                       const int* __restrict__ seg_s, const int* __restrict__ seg_e,
                       int* __restrict__ tok_st, int* __restrict__ tok_en,
                       int* __restrict__ tok_sg, int* __restrict__ ntok,
                       float* __restrict__ out_ntok) {
  int b = blockIdx.x, tid = threadIdx.x;
  __shared__ int toff[SEGSTRIDE];
  int ns = nsegp[b];
  if (tid == 0) {
    int acc = 0;
    for (int i = 0; i < ns; ++i) { toff[i] = acc; acc += ntokv[b * SEGSTRIDE + i]; }
    if (acc > MAXTOK) acc = MAXTOK;
    ntok[b] = acc;
    out_ntok[b] = (float)acc;
  }
  __syncthreads();
  for (int i = tid; i < ns; i += blockDim.x) {
    int base = toff[i];
    int s = seg_s[b * SEGSTRIDE + i], e = seg_e[b * SEGSTRIDE + i];
    int pl = plv[b * SEGSTRIDE + i];
    int Ls = e - s;
    int nf = Ls / pl;
    for (int t = 0; t < nf; ++t) {
      int g = base + t;
      if (g >= MAXTOK) break;
      tok_st[b * MAXTOK + g] = s + t * pl;
      tok_en[b * MAXTOK + g] = s + (t + 1) * pl;
      tok_sg[b * MAXTOK + g] = i;
    }
    if (nf * pl < Ls) {
      int g = base + nf;
      if (g < MAXTOK) {
        tok_st[b * MAXTOK + g] = s + nf * pl;
        tok_en[b * MAXTOK + g] = e;
        tok_sg[b * MAXTOK + g] = i;
      }
    }
  }
}

// ---------------- K7: metadata outputs (mask/so/eo/co/sp/rg), zero-filled beyond n_tok
__global__ void k_meta(const int* __restrict__ ntok,
                       const int* __restrict__ tok_st, const int* __restrict__ tok_en,
                       const int* __restrict__ tok_sg,
                       const float* __restrict__ dpv, const float* __restrict__ bwv,
                       const int* __restrict__ seg_s, const int* __restrict__ seg_e,
                       float* __restrict__ out, int N) {
  int idx = blockIdx.x * blockDim.x + threadIdx.x;
  if (idx >= BB * N) return;
  int b = idx / N, n = idx - b * N;
  float mask = 0, so = 0, eo = 0, co = 0, sp = 0, r0 = 0, r1 = 0, r2 = 0;
  if (n < ntok[b]) {
    int st = tok_st[b * MAXTOK + n], en = tok_en[b * MAXTOK + n], sg = tok_sg[b * MAXTOK + n];
    mask = 1.0f;
    so = (float)st; eo = (float)en;
    co = (float)(((double)st + (double)en - 1.0) * 0.5 / 8191.0);
    sp = (float)((double)(en - st) / 8192.0);
    r0 = (float)((double)dpv[b * SEGSTRIDE + sg] / 8192.0);
    r1 = bwv[b * SEGSTRIDE + sg];
    r2 = (float)((double)(seg_e[b * SEGSTRIDE + sg] - seg_s[b * SEGSTRIDE + sg]) / 8192.0);
  }
  size_t Nz = (size_t)N;
  size_t o1 = (size_t)32768 * Nz;       // after patches
  out[o1 + idx] = mask;                 // mask
  out[o1 + 32 * Nz + idx] = so;         // so
  out[o1 + 64 * Nz + idx] = eo;         // eo
  out[o1 + 96 * Nz + idx] = co;         // co
  out[o1 + 128 * Nz + idx] = sp;        // sp
  size_t o6 = o1 + 160 * Nz;            // rg
  out[o6 + (size_t)idx * 3 + 0] = r0;
  out[o6 + (size_t)idx * 3 + 1] = r1;
  out[o6 + (size_t)idx * 3 + 2] = r2;
}

// ---------------- K8: patch extraction with jax-matching linear resize to 16
__global__ void k_patches(const float* __restrict__ x,
                          const int* __restrict__ ntok,
                          const int* __restrict__ tok_st, const int* __restrict__ tok_en,
                          float* __restrict__ out, int N) {
  int blk = blockIdx.x;
  int b = blk / N, n = blk - b * N;
  size_t obase = (size_t)blk * (CC * ANCH);
  if (n >= ntok[b]) {
    for (int i = threadIdx.x; i < CC * ANCH; i += blockDim.x) out[obase + i] = 0.0f;
    return;
  }
  int st = tok_st[b * MAXTOK + n], en = tok_en[b * MAXTOK + n];
  int P = en - st;
  float scale = (float)((double)P / 16.0);
  float hi = (float)(P - 1);
  const float* xb = x + (size_t)b * CC * LL + st;
  for (int i = threadIdx.x; i < CC * ANCH; i += blockDim.x) {
    int c = i >> 4, k = i & 15;
    float pos = ((float)k + 0.5f) * scale - 0.5f;
    pos = fminf(fmaxf(pos, 0.0f), hi);
    int i0 = (int)floorf(pos);
    int i1 = min(i0 + 1, P - 1);
    float wgt = pos - (float)i0;
    const float* row = xb + (size_t)c * LL;
    out[obase + i] = row[i0] * (1.0f - wgt) + row[i1] * wgt;
  }
}

extern "C" void kernel_launch(void* const* d_in, const int* in_sizes, int n_in,
                              void* d_out, int out_size, void* d_ws, size_t ws_size,
                              hipStream_t stream) {
  const float* x = (const float*)d_in[0];
  float* out = (float*)d_out;
  // out_size = 33024*N + 32  (patches 32768N, mask/so/eo/co/sp 32N each, rg 96N, n_tok 32)
  int N = (out_size - BB) / 33024;
  if (N <= 0) return;

  char* ws = (char*)d_ws;
  size_t o = 0;
  auto A = [&](size_t bytes) { size_t r = o; o += (bytes + 255) & ~(size_t)255; return r; };
  float*  agg    = (float*) (ws + A((size_t)BB * LL * 4));
  float*  feat   = (float*) (ws + A((size_t)BB * 1024 * 3 * 4));
  int*    seg_s  = (int*)   (ws + A((size_t)BB * SEGSTRIDE * 4));
  int*    seg_e  = (int*)   (ws + A((size_t)BB * SEGSTRIDE * 4));
  int*    segoff = (int*)   (ws + A((size_t)BB * OFFSTRIDE * 4));
  int*    binseg = (int*)   (ws + A((size_t)BB * NBINS * 4));
  int*    nsegp  = (int*)   (ws + A((size_t)BB * 4));
  double* powb   = (double*)(ws + A((size_t)BB * NBINS * 8));
  float*  dpv    = (float*) (ws + A((size_t)BB * SEGSTRIDE * 4));
  float*  bwv    = (float*) (ws + A((size_t)BB * SEGSTRIDE * 4));
  int*    plv    = (int*)   (ws + A((size_t)BB * SEGSTRIDE * 4));
  int*    ntokv  = (int*)   (ws + A((size_t)BB * SEGSTRIDE * 4));
  int*    tok_st = (int*)   (ws + A((size_t)BB * MAXTOK * 4));
  int*    tok_en = (int*)   (ws + A((size_t)BB * MAXTOK * 4));
  int*    tok_sg = (int*)   (ws + A((size_t)BB * MAXTOK * 4));
  int*    ntok   = (int*)   (ws + A((size_t)BB * 4));
  (void)ws_size; (void)in_sizes; (void)n_in;

  k_agg<<<dim3((BB * LL + 255) / 256), dim3(256), 0, stream>>>(x, agg);
  k_winfeat<<<dim3(BB, (NW + 255) / 256), dim3(256), 0, stream>>>(agg, feat);
  k_dp<<<dim3(BB), dim3(512), 0, stream>>>(feat, seg_s, seg_e, nsegp, segoff, binseg);
  k_power<<<dim3(BB, NBINS / 256), dim3(256), 0, stream>>>(agg, seg_s, seg_e, segoff, binseg, powb);
  k_segstat<<<dim3(BB, SEGSTRIDE), dim3(64), 0, stream>>>(powb, seg_s, seg_e, segoff, nsegp,
                                                          dpv, bwv, plv, ntokv);
  k_plan<<<dim3(BB), dim3(256), 0, stream>>>(nsegp, ntokv, plv, seg_s, seg_e,
                                             tok_st, tok_en, tok_sg, ntok,
                                             out + (size_t)33024 * N);
  k_meta<<<dim3((BB * N + 255) / 256), dim3(256), 0, stream>>>(ntok, tok_st, tok_en, tok_sg,
                                                               dpv, bwv, seg_s, seg_e, out, N);
  k_patches<<<dim3(BB * N), dim3(256), 0, stream>>>(x, ntok, tok_st, tok_en, out, N);
}

// Round 6
// 1408.472 us; speedup vs baseline: 3.4298x; 1.0857x over previous
//
#include <hip/hip_runtime.h>
#include <math.h>

#define BB 32
#define CC 64
#define LL 8192
#define WIN 32
#define HOP 8
#define NW 1021          // (8192-32)/8 + 1
#define NT 1022          // NW + 1
#define NBINS 4096       // sum of Ls/2 over segments == LL/2
#define SEGSTRIDE 1024   // max segments per batch (each >= 8 samples)
#define OFFSTRIDE 1025
#define MAXTOK 2048
#define ANCH 16
#define TWO_PI 6.283185307179586476925286766559
#define DP_TILE 64
#define DP_WAVES 8

// ---------------- K1: channel mean (sequential f32 accumulation, matches numpy axis-0 reduce)
__global__ void k_agg(const float* __restrict__ x, float* __restrict__ agg) {
  int idx = blockIdx.x * blockDim.x + threadIdx.x;
  if (idx >= BB * LL) return;
  int b = idx / LL, l = idx - b * LL;
  const float* xp = x + (size_t)b * CC * LL + l;
  float acc = 0.0f;
  for (int c = 0; c < CC; ++c) acc += xp[(size_t)c * LL];
  agg[idx] = acc / 64.0f;
}

// ---------------- K2: per-window spectral features (f64 DFT len 32, bins 1..16), f32 cast
__global__ void k_winfeat(const float* __restrict__ agg, float* __restrict__ feat) {
  __shared__ double ct[32], st[32];
  int b = blockIdx.x;
  int w = blockIdx.y * blockDim.x + threadIdx.x;
  if (threadIdx.x < 32) {
    double ang = -TWO_PI * (double)threadIdx.x / 32.0;
    sincos(ang, &st[threadIdx.x], &ct[threadIdx.x]);
  }
  __syncthreads();
  if (w >= NW) return;
  const float* a = agg + b * LL + w * HOP;
  double p[17];
  for (int k = 1; k <= 16; ++k) {
    double re = 0.0, im = 0.0;
    int m = 0;
    for (int n = 0; n < 32; ++n) {
      double av = (double)a[n];
      re += av * ct[m];
      im += av * st[m];
      m = (m + k) & 31;
    }
    p[k] = re * re + im * im;
  }
  // numpy pairwise (16 elems): r[j] = x[j] + x[j+8]; ((r0+r1)+(r2+r3))+((r4+r5)+(r6+r7))
  double r[8];
  for (int j = 0; j < 8; ++j) r[j] = p[1 + j] + p[9 + j];
  double total = ((r[0] + r[1]) + (r[2] + r[3])) + ((r[4] + r[5]) + (r[6] + r[7]));
  double denom = total + 1e-12;
  double probs[17];
  for (int k = 1; k <= 16; ++k) probs[k] = p[k] / denom;
  for (int j = 0; j < 8; ++j)
    r[j] = probs[1 + j] * ((double)(1 + j) / 32.0) + probs[9 + j] * ((double)(9 + j) / 32.0);
  double centroid = ((r[0] + r[1]) + (r[2] + r[3])) + ((r[4] + r[5]) + (r[6] + r[7]));
  for (int j = 0; j < 8; ++j) {
    double f0 = (double)(1 + j) / 32.0 - centroid;
    double f1 = (double)(9 + j) / 32.0 - centroid;
    r[j] = probs[1 + j] * (f0 * f0) + probs[9 + j] * (f1 * f1);
  }
  double var = ((r[0] + r[1]) + (r[2] + r[3])) + ((r[4] + r[5]) + (r[6] + r[7]));
  double spread = sqrt(fmax(var, 0.0));
  size_t fo = ((size_t)b * 1024 + w) * 3;
  feat[fo + 0] = (float)centroid;
  feat[fo + 1] = (float)(2.0 * spread);
  feat[fo + 2] = (float)log1p(total / 32.0);
}

// ---------------- K3: PELT DP changepoints — tiled parallel scan (no pruning; full argmin)
// Tile of 64 t-values: phase 1 = min over prior j in [0,T0] (8 waves split j ascending,
// broadcast LDS reads, zero conflicts); phase 2 = within-tile j's resolved by wave 0
// via 63 dependent shuffle-broadcast steps. 2 barriers/tile (32 total vs 2042 in r1).
// Cost expression, association, exact f64 division, strict-< first-occurrence argmin
// and ascending-j merge order are bit-identical to the round-3 passing version.
__global__ void __launch_bounds__(512)
k_dp(const float* __restrict__ feat,
     int* __restrict__ seg_s, int* __restrict__ seg_e,
     int* __restrict__ nsegp, int* __restrict__ segoff, int* __restrict__ binseg) {
  int b = blockIdx.x, tid = threadIdx.x;
  int wv = tid >> 6, lane = tid & 63;
  __shared__ double cs[NT][3];               // 24528 B  per-dim cumsum
  __shared__ double q[NT];                   //  8176 B  sum-over-dims cumsum of squares
  __shared__ double G[NT];                   //  8176 B  F[j] - q[j]
  __shared__ short parent[NT];               //  2044 B
  __shared__ int soff[OFFSTRIDE];            //  4100 B
  __shared__ double redv[DP_WAVES][DP_TILE]; //  4096 B
  __shared__ int redi[DP_WAVES][DP_TILE];    //  2048 B
  __shared__ int ns_sh;                      //  => ~53.2 KB total (< 64 KB)

  if (tid == 0) {
    cs[0][0] = 0.0; cs[0][1] = 0.0; cs[0][2] = 0.0;
    q[0] = 0.0; G[0] = 0.0;
  }
  if (tid < 6) {  // lanes 0-2: feature cumsum dims; lanes 3-5: squared cumsum dims
    int d = tid % 3; bool sq = tid >= 3;
    double acc = 0.0;
    for (int i = 0; i < NW; ++i) {
      double v = (double)feat[((size_t)b * 1024 + i) * 3 + d];
      acc += sq ? v * v : v;
      if (!sq) cs[i + 1][d] = acc;
      double a4 = __shfl(acc, 4);       // lanes 3,4,5 active here
      double a5 = __shfl(acc, 5);
      if (tid == 3) q[i + 1] = (acc + a4) + a5;
    }
  }
  __syncthreads();

  const int ntiles = (NW + DP_TILE - 1) / DP_TILE;   // 16
  for (int g = 0; g < ntiles; ++g) {
    int T0 = g * DP_TILE;                    // prior j's: [0, T0]; t's: T0+1 .. T0+tcount
    int tcount = NW - T0; if (tcount > DP_TILE) tcount = DP_TILE;
    int t = T0 + 1 + lane;
    bool tvalid = lane < tcount;
    double ct0 = 0.0, ct1 = 0.0, ct2 = 0.0, Qt3 = 0.0;
    if (tvalid) { ct0 = cs[t][0]; ct1 = cs[t][1]; ct2 = cs[t][2]; Qt3 = q[t] + 3.0; }

    // ---- phase 1: min over j in [0, T0], waves take ascending chunks
    int njp = T0 + 1;
    int chunk = (njp + DP_WAVES - 1) / DP_WAVES;
    int j0 = wv * chunk;
    int j1 = j0 + chunk; if (j1 > njp) j1 = njp;
    double bv = INFINITY; int bj = 0x7fffffff;
    for (int j = j0; j < j1; ++j) {
      double c0 = cs[j][0], c1 = cs[j][1], c2 = cs[j][2], Gj = G[j]; // broadcast reads
      double d0 = ct0 - c0, d1 = ct1 - c1, d2 = ct2 - c2;
      double dd = (d0 * d0 + d1 * d1) + d2 * d2;
      double val = (Gj + Qt3) - dd / (double)(t - j);
      if (val < bv) { bv = val; bj = j; }   // ascending j => first occurrence
    }
    redv[wv][lane] = bv; redi[wv][lane] = bj;
    __syncthreads();

    if (wv == 0) {
      bv = redv[0][lane]; bj = redi[0][lane];
      for (int w = 1; w < DP_WAVES; ++w) {   // chunks ascend in j: tie keeps earlier wave
        double ov = redv[w][lane]; int oj = redi[w][lane];
        if (ov < bv || (ov == bv && oj < bj)) { bv = ov; bj = oj; }
      }
      // ---- phase 2: within-tile sequential resolution via shuffles
      for (int l2 = 0; l2 < tcount - 1; ++l2) {
        double Gj_self = bv - (Qt3 - 3.0);       // lane l2's F[t]-q[t] (final at step l2)
        double Gj  = __shfl(Gj_self, l2);
        double cj0 = __shfl(ct0, l2);
        double cj1 = __shfl(ct1, l2);
        double cj2 = __shfl(ct2, l2);
        if (tvalid && lane > l2) {
          double d0 = ct0 - cj0, d1 = ct1 - cj1, d2 = ct2 - cj2;
          double dd = (d0 * d0 + d1 * d1) + d2 * d2;
          double val = (Gj + Qt3) - dd / (double)(lane - l2);
          if (val < bv) { bv = val; bj = T0 + 1 + l2; }
        }
      }
      if (tvalid) { parent[t] = (short)bj; G[t] = bv - (Qt3 - 3.0); }
    }
    __syncthreads();
  }

  if (tid == 0) {
    short* path = (short*)&q[0];      // reuse LDS (<= 2044 B of 8176)
    int* sb = (int*)&G[0];            // reuse LDS (<= 4100 B of 8176)
    int cnt = 0, t = NW;
    while (t > 0) { t = parent[t]; path[cnt++] = (short)t; }
    int nb = 0, prev = 0;
    sb[nb++] = 0;
    for (int i = cnt - 2; i >= 0; --i) {   // wb[1:-1] in increasing order
      int w = path[i];
      int ti = w * HOP;
      if (ti <= prev) continue;
      if (ti - prev < 8) continue;   // PATCH_MIN
      if (LL - ti < 8) continue;
      sb[nb++] = ti; prev = ti;
    }
    sb[nb++] = LL;
    int ns = nb - 1;
    ns_sh = ns;
    nsegp[b] = ns;
    int off = 0;
    for (int i = 0; i < ns; ++i) { soff[i] = off; off += (sb[i + 1] - sb[i]) >> 1; }
    soff[ns] = off;   // == NBINS
  }
  __syncthreads();
  int ns = ns_sh;
  const int* sb = (const int*)&G[0];
  for (int i = tid; i < ns; i += 512) {
    seg_s[b * SEGSTRIDE + i] = sb[i];
    seg_e[b * SEGSTRIDE + i] = sb[i + 1];
    segoff[b * OFFSTRIDE + i] = soff[i];
    int o0 = soff[i], o1 = soff[i + 1];
    for (int qq = o0; qq < o1; ++qq) binseg[b * NBINS + qq] = i;
  }
  if (tid == 0) segoff[b * OFFSTRIDE + ns] = soff[ns];
}

// ---------------- K4: per-bin segment DFT power, 8 lanes per bin (strided rotators)
// Each 8-lane group shares a bin; lane handles n = lane8, lane8+8, ... with rotator
// stepping by w^(8k) and resync every 64 strided steps (same 512-sample drift budget
// as the serial version). 3-step shuffle tree combines partials (~1e-15 rel perturb,
// same scale as the already-passing recurrence deviation). 8x grid => full occupancy.
__global__ void __launch_bounds__(256)
k_power(const float* __restrict__ agg,
        const int* __restrict__ seg_s, const int* __restrict__ seg_e,
        const int* __restrict__ segoff, const int* __restrict__ binseg,
        double* __restrict__ powb) {
  int gid = blockIdx.x * 256 + threadIdx.x;          // over BB*NBINS*8
  int lane8 = gid & 7;
  int bino = gid >> 3;                               // 0..BB*NBINS-1
  int b = bino >> 12;                                // NBINS = 4096
  int bin = bino & (NBINS - 1);
  int seg = binseg[b * NBINS + bin];
  int s = seg_s[b * SEGSTRIDE + seg];
  int e = seg_e[b * SEGSTRIDE + seg];
  int Ls = e - s;
  int k = bin - segoff[b * OFFSTRIDE + seg] + 1;     // frequency index 1..Ls/2
  const float* a = agg + b * LL + s;
  double wr, wi;                                     // step = exp(-2pi i * 8k / Ls)
  sincos(-TWO_PI * (double)(8 * k) / (double)Ls, &wi, &wr);
  double cr, ci;                                     // start = exp(-2pi i * k*lane8 / Ls)
  sincos(-TWO_PI * (double)(k * lane8) / (double)Ls, &ci, &cr);
  double re = 0.0, im = 0.0;
  int j = 0;
  for (int n = lane8; n < Ls; n += 8, ++j) {
    if ((j & 63) == 0 && j) {        // resync to kill recurrence drift
      int m = (int)(((long long)k * n) % Ls);
      sincos(-TWO_PI * (double)m / (double)Ls, &ci, &cr);
    }
    double av = (double)a[n];
    re = fma(av, cr, re);
    im = fma(av, ci, im);
    double nr = cr * wr - ci * wi;
    ci = fma(cr, wi, ci * wr);
    cr = nr;
  }
  for (int off = 4; off; off >>= 1) {
    re += __shfl_down(re, off, 8);
    im += __shfl_down(im, off, 8);
  }
  if (lane8 == 0) powb[(size_t)b * NBINS + bin] = re * re + im * im;
}

// ---------------- K5: per-segment stats -> dom_period/bandwidth (f32), patch len, token count
__global__ void k_segstat(const double* __restrict__ powb,
                          const int* __restrict__ seg_s, const int* __restrict__ seg_e,
                          const int* __restrict__ segoff, const int* __restrict__ nsegp,
                          float* __restrict__ dpv, float* __restrict__ bwv,
                          int* __restrict__ plv, int* __restrict__ ntokv) {
  int b = blockIdx.x, sidx = blockIdx.y;
  if (sidx >= nsegp[b]) return;
  int lane = threadIdx.x;
  int s = seg_s[b * SEGSTRIDE + sidx], e = seg_e[b * SEGSTRIDE + sidx];
  int Ls = e - s;
  int K = Ls >> 1;
  const double* p = powb + (size_t)b * NBINS + segoff[b * OFFSTRIDE + sidx];
  double T = 0.0, mx = -1.0; int mi = 0x7fffffff;
  for (int j = lane; j < K; j += 64) {
    double pv = p[j];
    T += pv;
    if (pv > mx) { mx = pv; mi = j; }   // strict > keeps first occurrence per lane
  }
  for (int off = 32; off > 0; off >>= 1) {
    T += __shfl_down(T, off);
    double omx = __shfl_down(mx, off);
    int omi = __shfl_down(mi, off);
    if (omx > mx || (omx == mx && omi < mi)) { mx = omx; mi = omi; }
  }
  T = __shfl(T, 0); mi = __shfl(mi, 0);
  double denom = T + 1e-12;
  double cp = 0.0;
  for (int j = lane; j < K; j += 64) cp += p[j] * ((double)(j + 1) / (double)Ls);
  for (int off = 32; off > 0; off >>= 1) cp += __shfl_down(cp, off);
  double c = __shfl(cp, 0) / denom;
  double sp2 = 0.0;
  for (int j = lane; j < K; j += 64) {
    double d = (double)(j + 1) / (double)Ls - c;
    sp2 += p[j] * (d * d);
  }
  for (int off = 32; off > 0; off >>= 1) sp2 += __shfl_down(sp2, off);
  if (lane == 0) {
    double spread = sqrt(fmax(sp2 / denom, 0.0));
    float dp32 = (float)((double)Ls / ((double)mi + 1.0));
    float bw32 = (float)(2.0 * spread);
    double raw = (double)dp32 / (1.0 + (double)bw32);   // ALPHA=BETA=1
    int pl = (int)rint(raw * 0.5) * 2;                  // python round = half-even
    pl = pl < 8 ? 8 : (pl > 64 ? 64 : pl);
    int nf = Ls / pl;
    dpv[b * SEGSTRIDE + sidx] = dp32;
    bwv[b * SEGSTRIDE + sidx] = bw32;
    plv[b * SEGSTRIDE + sidx] = pl;
    ntokv[b * SEGSTRIDE + sidx] = nf + ((nf * pl < Ls) ? 1 : 0);
  }
}

// ---------------- K6: token plan (prefix offsets + token table) and n_tok output
__global__ void k_plan(const int* __restrict__ nsegp, const int* __restrict__ ntokv,
                       const int* __restrict__ plv,
                       const int* __restrict__ seg_s, const int* __restrict__ seg_e,
                       int* __restrict__ tok_st, int* __restrict__ tok_en,
                       int* __restrict__ tok_sg, int* __restrict__ ntok,
                       float* __restrict__ out_ntok) {
  int b = blockIdx.x, tid = threadIdx.x;
  __shared__ int toff[SEGSTRIDE];
  int ns = nsegp[b];
  if (tid == 0) {
    int acc = 0;
    for (int i = 0; i < ns; ++i) { toff[i] = acc; acc += ntokv[b * SEGSTRIDE + i]; }
    if (acc > MAXTOK) acc = MAXTOK;
    ntok[b] = acc;
    out_ntok[b] = (float)acc;
  }
  __syncthreads();
  for (int i = tid; i < ns; i += blockDim.x) {
    int base = toff[i];
    int s = seg_s[b * SEGSTRIDE + i], e = seg_e[b * SEGSTRIDE + i];
    int pl = plv[b * SEGSTRIDE + i];
    int Ls = e - s;
    int nf = Ls / pl;
    for (int t = 0; t < nf; ++t) {
      int g = base + t;
      if (g >= MAXTOK) break;
      tok_st[b * MAXTOK + g] = s + t * pl;
      tok_en[b * MAXTOK + g] = s + (t + 1) * pl;
      tok_sg[b * MAXTOK + g] = i;
    }
    if (nf * pl < Ls) {
      int g = base + nf;
      if (g < MAXTOK) {
        tok_st[b * MAXTOK + g] = s + nf * pl;
        tok_en[b * MAXTOK + g] = e;
        tok_sg[b * MAXTOK + g] = i;
      }
    }
  }
}

// ---------------- K7: metadata outputs (mask/so/eo/co/sp/rg), zero-filled beyond n_tok
__global__ void k_meta(const int* __restrict__ ntok,
                       const int* __restrict__ tok_st, const int* __restrict__ tok_en,
                       const int* __restrict__ tok_sg,
                       const float* __restrict__ dpv, const float* __restrict__ bwv,
                       const int* __restrict__ seg_s, const int* __restrict__ seg_e,
                       float* __restrict__ out, int N) {
  int idx = blockIdx.x * blockDim.x + threadIdx.x;
  if (idx >= BB * N) return;
  int b = idx / N, n = idx - b * N;
  float mask = 0, so = 0, eo = 0, co = 0, sp = 0, r0 = 0, r1 = 0, r2 = 0;
  if (n < ntok[b]) {
    int st = tok_st[b * MAXTOK + n], en = tok_en[b * MAXTOK + n], sg = tok_sg[b * MAXTOK + n];
    mask = 1.0f;
    so = (float)st; eo = (float)en;
    co = (float)(((double)st + (double)en - 1.0) * 0.5 / 8191.0);
    sp = (float)((double)(en - st) / 8192.0);
    r0 = (float)((double)dpv[b * SEGSTRIDE + sg] / 8192.0);
    r1 = bwv[b * SEGSTRIDE + sg];
    r2 = (float)((double)(seg_e[b * SEGSTRIDE + sg] - seg_s[b * SEGSTRIDE + sg]) / 8192.0);
  }
  size_t Nz = (size_t)N;
  size_t o1 = (size_t)32768 * Nz;       // after patches
  out[o1 + idx] = mask;                 // mask
  out[o1 + 32 * Nz + idx] = so;         // so
  out[o1 + 64 * Nz + idx] = eo;         // eo
  out[o1 + 96 * Nz + idx] = co;         // co
  out[o1 + 128 * Nz + idx] = sp;        // sp
  size_t o6 = o1 + 160 * Nz;            // rg
  out[o6 + (size_t)idx * 3 + 0] = r0;
  out[o6 + (size_t)idx * 3 + 1] = r1;
  out[o6 + (size_t)idx * 3 + 2] = r2;
}

// ---------------- K8: patch extraction with jax-matching linear resize to 16
__global__ void k_patches(const float* __restrict__ x,
                          const int* __restrict__ ntok,
                          const int* __restrict__ tok_st, const int* __restrict__ tok_en,
                          float* __restrict__ out, int N) {
  int blk = blockIdx.x;
  int b = blk / N, n = blk - b * N;
  size_t obase = (size_t)blk * (CC * ANCH);
  if (n >= ntok[b]) {
    for (int i = threadIdx.x; i < CC * ANCH; i += blockDim.x) out[obase + i] = 0.0f;
    return;
  }
  int st = tok_st[b * MAXTOK + n], en = tok_en[b * MAXTOK + n];
  int P = en - st;
  float scale = (float)((double)P / 16.0);
  float hi = (float)(P - 1);
  const float* xb = x + (size_t)b * CC * LL + st;
  for (int i = threadIdx.x; i < CC * ANCH; i += blockDim.x) {
    int c = i >> 4, k = i & 15;
    float pos = ((float)k + 0.5f) * scale - 0.5f;
    pos = fminf(fmaxf(pos, 0.0f), hi);
    int i0 = (int)floorf(pos);
    int i1 = min(i0 + 1, P - 1);
    float wgt = pos - (float)i0;
    const float* row = xb + (size_t)c * LL;
    out[obase + i] = row[i0] * (1.0f - wgt) + row[i1] * wgt;
  }
}

extern "C" void kernel_launch(void* const* d_in, const int* in_sizes, int n_in,
                              void* d_out, int out_size, void* d_ws, size_t ws_size,
                              hipStream_t stream) {
  const float* x = (const float*)d_in[0];
  float* out = (float*)d_out;
  // out_size = 33024*N + 32  (patches 32768N, mask/so/eo/co/sp 32N each, rg 96N, n_tok 32)
  int N = (out_size - BB) / 33024;
  if (N <= 0) return;

  char* ws = (char*)d_ws;
  size_t o = 0;
  auto A = [&](size_t bytes) { size_t r = o; o += (bytes + 255) & ~(size_t)255; return r; };
  float*  agg    = (float*) (ws + A((size_t)BB * LL * 4));
  float*  feat   = (float*) (ws + A((size_t)BB * 1024 * 3 * 4));
  int*    seg_s  = (int*)   (ws + A((size_t)BB * SEGSTRIDE * 4));
  int*    seg_e  = (int*)   (ws + A((size_t)BB * SEGSTRIDE * 4));
  int*    segoff = (int*)   (ws + A((size_t)BB * OFFSTRIDE * 4));
  int*    binseg = (int*)   (ws + A((size_t)BB * NBINS * 4));
  int*    nsegp  = (int*)   (ws + A((size_t)BB * 4));
  double* powb   = (double*)(ws + A((size_t)BB * NBINS * 8));
  float*  dpv    = (float*) (ws + A((size_t)BB * SEGSTRIDE * 4));
  float*  bwv    = (float*) (ws + A((size_t)BB * SEGSTRIDE * 4));
  int*    plv    = (int*)   (ws + A((size_t)BB * SEGSTRIDE * 4));
  int*    ntokv  = (int*)   (ws + A((size_t)BB * SEGSTRIDE * 4));
  int*    tok_st = (int*)   (ws + A((size_t)BB * MAXTOK * 4));
  int*    tok_en = (int*)   (ws + A((size_t)BB * MAXTOK * 4));
  int*    tok_sg = (int*)   (ws + A((size_t)BB * MAXTOK * 4));
  int*    ntok   = (int*)   (ws + A((size_t)BB * 4));
  (void)ws_size; (void)in_sizes; (void)n_in;

  k_agg<<<dim3((BB * LL + 255) / 256), dim3(256), 0, stream>>>(x, agg);
  k_winfeat<<<dim3(BB, (NW + 255) / 256), dim3(256), 0, stream>>>(agg, feat);
  k_dp<<<dim3(BB), dim3(512), 0, stream>>>(feat, seg_s, seg_e, nsegp, segoff, binseg);
  k_power<<<dim3(BB * NBINS * 8 / 256), dim3(256), 0, stream>>>(agg, seg_s, seg_e, segoff, binseg, powb);
  k_segstat<<<dim3(BB, SEGSTRIDE), dim3(64), 0, stream>>>(powb, seg_s, seg_e, segoff, nsegp,
                                                          dpv, bwv, plv, ntokv);
  k_plan<<<dim3(BB), dim3(256), 0, stream>>>(nsegp, ntokv, plv, seg_s, seg_e,
                                             tok_st, tok_en, tok_sg, ntok,
                                             out + (size_t)33024 * N);
  k_meta<<<dim3((BB * N + 255) / 256), dim3(256), 0, stream>>>(ntok, tok_st, tok_en, tok_sg,
                                                               dpv, bwv, seg_s, seg_e, out, N);
  k_patches<<<dim3(BB * N), dim3(256), 0, stream>>>(x, ntok, tok_st, tok_en, out, N);
}

// Round 8
// 1267.877 us; speedup vs baseline: 3.8101x; 1.1109x over previous
//
#include <hip/hip_runtime.h>
#include <math.h>

#define BB 32
#define CC 64
#define LL 8192
#define WIN 32
#define HOP 8
#define NW 1021          // (8192-32)/8 + 1
#define NT 1022          // NW + 1
#define NBINS 4096       // sum of Ls/2 over segments == LL/2
#define SEGSTRIDE 1024   // max segments per batch (each >= 8 samples)
#define OFFSTRIDE 1025
#define MAXTOK 2048
#define ANCH 16
#define TWO_PI 6.283185307179586476925286766559
#define DP_TILE 64
#define DP_WAVES 8

// ---------------- K1: channel mean (sequential f32 accumulation, matches numpy axis-0 reduce)
__global__ void k_agg(const float* __restrict__ x, float* __restrict__ agg) {
  int idx = blockIdx.x * blockDim.x + threadIdx.x;
  if (idx >= BB * LL) return;
  int b = idx / LL, l = idx - b * LL;
  const float* xp = x + (size_t)b * CC * LL + l;
  float acc = 0.0f;
  for (int c = 0; c < CC; ++c) acc += xp[(size_t)c * LL];
  agg[idx] = acc / 64.0f;
}

// ---------------- K2: per-window spectral features (f64 DFT len 32, bins 1..16), f32 cast
__global__ void k_winfeat(const float* __restrict__ agg, float* __restrict__ feat) {
  __shared__ double ct[32], st[32];
  int b = blockIdx.x;
  int w = blockIdx.y * blockDim.x + threadIdx.x;
  if (threadIdx.x < 32) {
    double ang = -TWO_PI * (double)threadIdx.x / 32.0;
    sincos(ang, &st[threadIdx.x], &ct[threadIdx.x]);
  }
  __syncthreads();
  if (w >= NW) return;
  const float* a = agg + b * LL + w * HOP;
  double p[17];
  for (int k = 1; k <= 16; ++k) {
    double re = 0.0, im = 0.0;
    int m = 0;
    for (int n = 0; n < 32; ++n) {
      double av = (double)a[n];
      re += av * ct[m];
      im += av * st[m];
      m = (m + k) & 31;
    }
    p[k] = re * re + im * im;
  }
  // numpy pairwise (16 elems): r[j] = x[j] + x[j+8]; ((r0+r1)+(r2+r3))+((r4+r5)+(r6+r7))
  double r[8];
  for (int j = 0; j < 8; ++j) r[j] = p[1 + j] + p[9 + j];
  double total = ((r[0] + r[1]) + (r[2] + r[3])) + ((r[4] + r[5]) + (r[6] + r[7]));
  double denom = total + 1e-12;
  double probs[17];
  for (int k = 1; k <= 16; ++k) probs[k] = p[k] / denom;
  for (int j = 0; j < 8; ++j)
    r[j] = probs[1 + j] * ((double)(1 + j) / 32.0) + probs[9 + j] * ((double)(9 + j) / 32.0);
  double centroid = ((r[0] + r[1]) + (r[2] + r[3])) + ((r[4] + r[5]) + (r[6] + r[7]));
  for (int j = 0; j < 8; ++j) {
    double f0 = (double)(1 + j) / 32.0 - centroid;
    double f1 = (double)(9 + j) / 32.0 - centroid;
    r[j] = probs[1 + j] * (f0 * f0) + probs[9 + j] * (f1 * f1);
  }
  double var = ((r[0] + r[1]) + (r[2] + r[3])) + ((r[4] + r[5]) + (r[6] + r[7]));
  double spread = sqrt(fmax(var, 0.0));
  size_t fo = ((size_t)b * 1024 + w) * 3;
  feat[fo + 0] = (float)centroid;
  feat[fo + 1] = (float)(2.0 * spread);
  feat[fo + 2] = (float)log1p(total / 32.0);
}

// ---------------- K3: PELT DP changepoints — tiled parallel scan (no pruning; full argmin)
__global__ void __launch_bounds__(512)
k_dp(const float* __restrict__ feat,
     int* __restrict__ seg_s, int* __restrict__ seg_e,
     int* __restrict__ nsegp, int* __restrict__ segoff, int* __restrict__ binseg,
     int* __restrict__ smap) {                 // smap may be nullptr (fallback path)
  int b = blockIdx.x, tid = threadIdx.x;
  int wv = tid >> 6, lane = tid & 63;
  __shared__ double cs[NT][3];               // 24528 B  per-dim cumsum
  __shared__ double q[NT];                   //  8176 B  sum-over-dims cumsum of squares
  __shared__ double G[NT];                   //  8176 B  F[j] - q[j]
  __shared__ short parent[NT];               //  2044 B
  __shared__ int soff[OFFSTRIDE];            //  4100 B
  __shared__ double redv[DP_WAVES][DP_TILE]; //  4096 B
  __shared__ int redi[DP_WAVES][DP_TILE];    //  2048 B
  __shared__ int ns_sh;                      //  => ~53.2 KB total (< 64 KB)

  if (tid == 0) {
    cs[0][0] = 0.0; cs[0][1] = 0.0; cs[0][2] = 0.0;
    q[0] = 0.0; G[0] = 0.0;
  }
  if (tid < 6) {  // lanes 0-2: feature cumsum dims; lanes 3-5: squared cumsum dims
    int d = tid % 3; bool sq = tid >= 3;
    double acc = 0.0;
    for (int i = 0; i < NW; ++i) {
      double v = (double)feat[((size_t)b * 1024 + i) * 3 + d];
      acc += sq ? v * v : v;
      if (!sq) cs[i + 1][d] = acc;
      double a4 = __shfl(acc, 4);       // lanes 3,4,5 active here
      double a5 = __shfl(acc, 5);
      if (tid == 3) q[i + 1] = (acc + a4) + a5;
    }
  }
  __syncthreads();

  const int ntiles = (NW + DP_TILE - 1) / DP_TILE;   // 16
  for (int g = 0; g < ntiles; ++g) {
    int T0 = g * DP_TILE;                    // prior j's: [0, T0]; t's: T0+1 .. T0+tcount
    int tcount = NW - T0; if (tcount > DP_TILE) tcount = DP_TILE;
    int t = T0 + 1 + lane;
    bool tvalid = lane < tcount;
    double ct0 = 0.0, ct1 = 0.0, ct2 = 0.0, Qt3 = 0.0;
    if (tvalid) { ct0 = cs[t][0]; ct1 = cs[t][1]; ct2 = cs[t][2]; Qt3 = q[t] + 3.0; }

    // ---- phase 1: min over j in [0, T0], waves take ascending chunks
    int njp = T0 + 1;
    int chunk = (njp + DP_WAVES - 1) / DP_WAVES;
    int j0 = wv * chunk;
    int j1 = j0 + chunk; if (j1 > njp) j1 = njp;
    double bv = INFINITY; int bj = 0x7fffffff;
    for (int j = j0; j < j1; ++j) {
      double c0 = cs[j][0], c1 = cs[j][1], c2 = cs[j][2], Gj = G[j]; // broadcast reads
      double d0 = ct0 - c0, d1 = ct1 - c1, d2 = ct2 - c2;
      double dd = (d0 * d0 + d1 * d1) + d2 * d2;
      double val = (Gj + Qt3) - dd / (double)(t - j);
      if (val < bv) { bv = val; bj = j; }   // ascending j => first occurrence
    }
    redv[wv][lane] = bv; redi[wv][lane] = bj;
    __syncthreads();

    if (wv == 0) {
      bv = redv[0][lane]; bj = redi[0][lane];
      for (int w = 1; w < DP_WAVES; ++w) {   // chunks ascend in j: tie keeps earlier wave
        double ov = redv[w][lane]; int oj = redi[w][lane];
        if (ov < bv || (ov == bv && oj < bj)) { bv = ov; bj = oj; }
      }
      // ---- phase 2: within-tile sequential resolution via shuffles
      for (int l2 = 0; l2 < tcount - 1; ++l2) {
        double Gj_self = bv - (Qt3 - 3.0);       // lane l2's F[t]-q[t] (final at step l2)
        double Gj  = __shfl(Gj_self, l2);
        double cj0 = __shfl(ct0, l2);
        double cj1 = __shfl(ct1, l2);
        double cj2 = __shfl(ct2, l2);
        if (tvalid && lane > l2) {
          double d0 = ct0 - cj0, d1 = ct1 - cj1, d2 = ct2 - cj2;
          double dd = (d0 * d0 + d1 * d1) + d2 * d2;
          double val = (Gj + Qt3) - dd / (double)(lane - l2);
          if (val < bv) { bv = val; bj = T0 + 1 + l2; }
        }
      }
      if (tvalid) { parent[t] = (short)bj; G[t] = bv - (Qt3 - 3.0); }
    }
    __syncthreads();
  }

  if (tid == 0) {
    short* path = (short*)&q[0];      // reuse LDS (<= 2044 B of 8176)
    int* sb = (int*)&G[0];            // reuse LDS (<= 4100 B of 8176)
    int cnt = 0, t = NW;
    while (t > 0) { t = parent[t]; path[cnt++] = (short)t; }
    int nb = 0, prev = 0;
    sb[nb++] = 0;
    for (int i = cnt - 2; i >= 0; --i) {   // wb[1:-1] in increasing order
      int w = path[i];
      int ti = w * HOP;
      if (ti <= prev) continue;
      if (ti - prev < 8) continue;   // PATCH_MIN
      if (LL - ti < 8) continue;
      sb[nb++] = ti; prev = ti;
    }
    sb[nb++] = LL;
    int ns = nb - 1;
    ns_sh = ns;
    nsegp[b] = ns;
    int off = 0;
    for (int i = 0; i < ns; ++i) { soff[i] = off; off += (sb[i + 1] - sb[i]) >> 1; }
    soff[ns] = off;   // == NBINS
  }
  __syncthreads();
  int ns = ns_sh;
  const int* sb = (const int*)&G[0];
  for (int i = tid; i < ns; i += 512) {
    seg_s[b * SEGSTRIDE + i] = sb[i];
    seg_e[b * SEGSTRIDE + i] = sb[i + 1];
    segoff[b * OFFSTRIDE + i] = soff[i];
    int o0 = soff[i], o1 = soff[i + 1];
    for (int qq = o0; qq < o1; ++qq) binseg[b * NBINS + qq] = i;
    if (smap) {
      for (int p = sb[i]; p < sb[i + 1]; ++p) smap[b * LL + p] = i;   // sample -> segment
    }
  }
  if (tid == 0) segoff[b * OFFSTRIDE + ns] = soff[ns];
}

// ---------------- K4 (fallback): per-bin segment DFT power, 8 lanes per bin (round-6, proven)
__global__ void __launch_bounds__(256)
k_power8(const float* __restrict__ agg,
         const int* __restrict__ seg_s, const int* __restrict__ seg_e,
         const int* __restrict__ segoff, const int* __restrict__ binseg,
         double* __restrict__ powb) {
  int gid = blockIdx.x * 256 + threadIdx.x;          // over BB*NBINS*8
  int lane8 = gid & 7;
  int bino = gid >> 3;                               // 0..BB*NBINS-1
  int b = bino >> 12;                                // NBINS = 4096
  int bin = bino & (NBINS - 1);
  int seg = binseg[b * NBINS + bin];
  int s = seg_s[b * SEGSTRIDE + seg];
  int e = seg_e[b * SEGSTRIDE + seg];
  int Ls = e - s;
  int k = bin - segoff[b * OFFSTRIDE + seg] + 1;     // frequency index 1..Ls/2
  const float* a = agg + b * LL + s;
  double wr, wi;                                     // step = exp(-2pi i * 8k / Ls)
  sincos(-TWO_PI * (double)(8 * k) / (double)Ls, &wi, &wr);
  double cr, ci;                                     // start = exp(-2pi i * k*lane8 / Ls)
  sincos(-TWO_PI * (double)(k * lane8) / (double)Ls, &ci, &cr);
  double re = 0.0, im = 0.0;
  int j = 0;
  for (int n = lane8; n < Ls; n += 8, ++j) {
    if ((j & 63) == 0 && j) {        // resync to kill recurrence drift
      int m = (int)(((long long)k * n) % Ls);
      sincos(-TWO_PI * (double)m / (double)Ls, &ci, &cr);
    }
    double av = (double)a[n];
    re = fma(av, cr, re);
    im = fma(av, ci, im);
    double nr = cr * wr - ci * wi;
    ci = fma(cr, wi, ci * wr);
    cr = nr;
  }
  for (int off = 4; off; off >>= 1) {
    re += __shfl_down(re, off, 8);
    im += __shfl_down(im, off, 8);
  }
  if (lane8 == 0) powb[(size_t)b * NBINS + bin] = re * re + im * im;
}

// ---------------- K4a: radix-8 inner sub-DFTs. Segment lengths are multiples of 8
// (all boundaries are multiples of HOP=8). n = 8m + r:
//   S_r[q] = sum_m a[8m+r] * exp(-2pi i q m / M),  M = Ls/8, q in [0,M), r in [0,8).
// Work = sum Ls^2/8 sample-iters (4x less than direct Ls^2/2). Inner task index
// p = s + q*8 + r tiles [0,LL) exactly; 8 lanes per task, strided rotators with
// resync every 64 steps.
__global__ void __launch_bounds__(256)
k_power1(const float* __restrict__ agg,
         const int* __restrict__ seg_s, const int* __restrict__ seg_e,
         const int* __restrict__ smap,
         double* __restrict__ sub) {           // complex interleaved, BB*LL*2 doubles
  int gid = blockIdx.x * 256 + threadIdx.x;    // over BB*LL*8
  int lane8 = gid & 7;
  int po = gid >> 3;                           // 0..BB*LL-1
  int b = po >> 13;                            // LL = 8192
  int p = po & (LL - 1);
  int seg = smap[b * LL + p];
  int s = seg_s[b * SEGSTRIDE + seg];
  int Ls = seg_e[b * SEGSTRIDE + seg] - s;
  int M = Ls >> 3;
  int i = p - s;
  int q = i >> 3, r = i & 7;
  const float* a = agg + b * LL + s;
  double wr, wi;                               // step = exp(-2pi i * q*8 / M)
  sincos(-TWO_PI * (double)(8 * q) / (double)M, &wi, &wr);
  double cr, ci;                               // start = exp(-2pi i * q*lane8 / M)
  sincos(-TWO_PI * (double)(q * lane8) / (double)M, &ci, &cr);
  double re = 0.0, im = 0.0;
  int j = 0;
  for (int m = lane8; m < M; m += 8, ++j) {
    if ((j & 63) == 0 && j) {                  // resync to kill recurrence drift
      int mm = (int)(((long long)q * m) % M);
      sincos(-TWO_PI * (double)mm / (double)M, &ci, &cr);
    }
    double av = (double)a[(m << 3) + r];
    re = fma(av, cr, re);
    im = fma(av, ci, im);
    double nr = cr * wr - ci * wi;
    ci = fma(cr, wi, ci * wr);
    cr = nr;
  }
  for (int off = 4; off; off >>= 1) {
    re += __shfl_down(re, off, 8);
    im += __shfl_down(im, off, 8);
  }
  if (lane8 == 0) {
    size_t o = ((size_t)b * LL + p) * 2;
    sub[o] = re; sub[o + 1] = im;
  }
}

// ---------------- K4b: combine. X_k = sum_r W_Ls^{kr} * S_r[k mod M] via Horner.
__global__ void __launch_bounds__(256)
k_power2(const double* __restrict__ sub,
         const int* __restrict__ seg_s, const int* __restrict__ seg_e,
         const int* __restrict__ segoff, const int* __restrict__ binseg,
         double* __restrict__ powb) {
  int gid = blockIdx.x * 256 + threadIdx.x;    // over BB*NBINS
  int b = gid >> 12;                           // NBINS = 4096
  int bin = gid & (NBINS - 1);
  int seg = binseg[b * NBINS + bin];
  int s = seg_s[b * SEGSTRIDE + seg];
  int Ls = seg_e[b * SEGSTRIDE + seg] - s;
  int M = Ls >> 3;
  int k = bin - segoff[b * OFFSTRIDE + seg] + 1;   // 1..Ls/2
  int q0 = k - (k / M) * M;                        // k mod M
  const double* S = sub + ((size_t)b * LL + s + q0 * 8) * 2;  // 8 complex, contiguous
  double wr, wi;
  sincos(-TWO_PI * (double)k / (double)Ls, &wi, &wr);
  double xr = S[14], xi = S[15];
  for (int r = 6; r >= 0; --r) {               // Horner: ((S7*w+S6)*w+...)*w+S0
    double nr = (xr * wr - xi * wi) + S[2 * r];
    xi = (xr * wi + xi * wr) + S[2 * r + 1];
    xr = nr;
  }
  powb[(size_t)b * NBINS + bin] = xr * xr + xi * xi;
}

// ---------------- K5: per-segment stats -> dom_period/bandwidth (f32), patch len, token count
__global__ void k_segstat(const double* __restrict__ powb,
                          const int* __restrict__ seg_s, const int* __restrict__ seg_e,
                          const int* __restrict__ segoff, const int* __restrict__ nsegp,
                          float* __restrict__ dpv, float* __restrict__ bwv,
                          int* __restrict__ plv, int* __restrict__ ntokv) {
  int b = blockIdx.x, sidx = blockIdx.y;
  if (sidx >= nsegp[b]) return;
  int lane = threadIdx.x;
  int s = seg_s[b * SEGSTRIDE + sidx], e = seg_e[b * SEGSTRIDE + sidx];
  int Ls = e - s;
  int K = Ls >> 1;
  const double* p = powb + (size_t)b * NBINS + segoff[b * OFFSTRIDE + sidx];
  double T = 0.0, mx = -1.0; int mi = 0x7fffffff;
  for (int j = lane; j < K; j += 64) {
    double pv = p[j];
    T += pv;
    if (pv > mx) { mx = pv; mi = j; }   // strict > keeps first occurrence per lane
  }
  for (int off = 32; off > 0; off >>= 1) {
    T += __shfl_down(T, off);
    double omx = __shfl_down(mx, off);
    int omi = __shfl_down(mi, off);
    if (omx > mx || (omx == mx && omi < mi)) { mx = omx; mi = omi; }
  }
  T = __shfl(T, 0); mi = __shfl(mi, 0);
  double denom = T + 1e-12;
  double cp = 0.0;
  for (int j = lane; j < K; j += 64) cp += p[j] * ((double)(j + 1) / (double)Ls);
  for (int off = 32; off > 0; off >>= 1) cp += __shfl_down(cp, off);
  double c = __shfl(cp, 0) / denom;
  double sp2 = 0.0;
  for (int j = lane; j < K; j += 64) {
    double d = (double)(j + 1) / (double)Ls - c;
    sp2 += p[j] * (d * d);
  }
  for (int off = 32; off > 0; off >>= 1) sp2 += __shfl_down(sp2, off);
  if (lane == 0) {
    double spread = sqrt(fmax(sp2 / denom, 0.0));
    float dp32 = (float)((double)Ls / ((double)mi + 1.0));
    float bw32 = (float)(2.0 * spread);
    double raw = (double)dp32 / (1.0 + (double)bw32);   // ALPHA=BETA=1
    int pl = (int)rint(raw * 0.5) * 2;                  // python round = half-even
    pl = pl < 8 ? 8 : (pl > 64 ? 64 : pl);
    int nf = Ls / pl;
    dpv[b * SEGSTRIDE + sidx] = dp32;
    bwv[b * SEGSTRIDE + sidx] = bw32;
    plv[b * SEGSTRIDE + sidx] = pl;
    ntokv[b * SEGSTRIDE + sidx] = nf + ((nf * pl < Ls) ? 1 : 0);
  }
}

// ---------------- K6: token plan (prefix offsets + token table) and n_tok output
__global__ void k_plan(const int* __restrict__ nsegp, const int* __restrict__ ntokv,
                       const int* __restrict__ plv,
                       const int* __restrict__ seg_s, const int* __restrict__ seg_e,
                       int* __restrict__ tok_st, int* __restrict__ tok_en,
                       int* __restrict__ tok_sg, int* __restrict__ ntok,
                       float* __restrict__ out_ntok) {
  int b = blockIdx.x, tid = threadIdx.x;
  __shared__ int toff[SEGSTRIDE];
  int ns = nsegp[b];
  if (tid == 0) {
    int acc = 0;
    for (int i = 0; i < ns; ++i) { toff[i] = acc; acc += ntokv[b * SEGSTRIDE + i]; }
    if (acc > MAXTOK) acc = MAXTOK;
    ntok[b] = acc;
    out_ntok[b] = (float)acc;
  }
  __syncthreads();
  for (int i = tid; i < ns; i += blockDim.x) {
    int base = toff[i];
    int s = seg_s[b * SEGSTRIDE + i], e = seg_e[b * SEGSTRIDE + i];
    int pl = plv[b * SEGSTRIDE + i];
    int Ls = e - s;
    int nf = Ls / pl;
    for (int t = 0; t < nf; ++t) {
      int g = base + t;
      if (g >= MAXTOK) break;
      tok_st[b * MAXTOK + g] = s + t * pl;
      tok_en[b * MAXTOK + g] = s + (t + 1) * pl;
      tok_sg[b * MAXTOK + g] = i;
    }
    if (nf * pl < Ls) {
      int g = base + nf;
      if (g < MAXTOK) {
        tok_st[b * MAXTOK + g] = s + nf * pl;
        tok_en[b * MAXTOK + g] = e;
        tok_sg[b * MAXTOK + g] = i;
      }
    }
  }
}

// ---------------- K7: metadata outputs (mask/so/eo/co/sp/rg), zero-filled beyond n_tok
__global__ void k_meta(const int* __restrict__ ntok,
                       const int* __restrict__ tok_st, const int* __restrict__ tok_en,
                       const int* __restrict__ tok_sg,
                       const float* __restrict__ dpv, const float* __restrict__ bwv,
                       const int* __restrict__ seg_s, const int* __restrict__ seg_e,
                       float* __restrict__ out, int N) {
  int idx = blockIdx.x * blockDim.x + threadIdx.x;
  if (idx >= BB * N) return;
  int b = idx / N, n = idx - b * N;
  float mask = 0, so = 0, eo = 0, co = 0, sp = 0, r0 = 0, r1 = 0, r2 = 0;
  if (n < ntok[b]) {
    int st = tok_st[b * MAXTOK + n], en = tok_en[b * MAXTOK + n], sg = tok_sg[b * MAXTOK + n];
    mask = 1.0f;
    so = (float)st; eo = (float)en;
    co = (float)(((double)st + (double)en - 1.0) * 0.5 / 8191.0);
    sp = (float)((double)(en - st) / 8192.0);
    r0 = (float)((double)dpv[b * SEGSTRIDE + sg] / 8192.0);
    r1 = bwv[b * SEGSTRIDE + sg];
    r2 = (float)((double)(seg_e[b * SEGSTRIDE + sg] - seg_s[b * SEGSTRIDE + sg]) / 8192.0);
  }
  size_t Nz = (size_t)N;
  size_t o1 = (size_t)32768 * Nz;       // after patches
  out[o1 + idx] = mask;                 // mask
  out[o1 + 32 * Nz + idx] = so;         // so
  out[o1 + 64 * Nz + idx] = eo;         // eo
  out[o1 + 96 * Nz + idx] = co;         // co
  out[o1 + 128 * Nz + idx] = sp;        // sp
  size_t o6 = o1 + 160 * Nz;            // rg
  out[o6 + (size_t)idx * 3 + 0] = r0;
  out[o6 + (size_t)idx * 3 + 1] = r1;
  out[o6 + (size_t)idx * 3 + 2] = r2;
}

// ---------------- K8: patch extraction with jax-matching linear resize to 16
__global__ void k_patches(const float* __restrict__ x,
                          const int* __restrict__ ntok,
                          const int* __restrict__ tok_st, const int* __restrict__ tok_en,
                          float* __restrict__ out, int N) {
  int blk = blockIdx.x;
  int b = blk / N, n = blk - b * N;
  size_t obase = (size_t)blk * (CC * ANCH);
  if (n >= ntok[b]) {
    for (int i = threadIdx.x; i < CC * ANCH; i += blockDim.x) out[obase + i] = 0.0f;
    return;
  }
  int st = tok_st[b * MAXTOK + n], en = tok_en[b * MAXTOK + n];
  int P = en - st;
  float scale = (float)((double)P / 16.0);
  float hi = (float)(P - 1);
  const float* xb = x + (size_t)b * CC * LL + st;
  for (int i = threadIdx.x; i < CC * ANCH; i += blockDim.x) {
    int c = i >> 4, k = i & 15;
    float pos = ((float)k + 0.5f) * scale - 0.5f;
    pos = fminf(fmaxf(pos, 0.0f), hi);
    int i0 = (int)floorf(pos);
    int i1 = min(i0 + 1, P - 1);
    float wgt = pos - (float)i0;
    const float* row = xb + (size_t)c * LL;
    out[obase + i] = row[i0] * (1.0f - wgt) + row[i1] * wgt;
  }
}

extern "C" void kernel_launch(void* const* d_in, const int* in_sizes, int n_in,
                              void* d_out, int out_size, void* d_ws, size_t ws_size,
                              hipStream_t stream) {
  const float* x = (const float*)d_in[0];
  float* out = (float*)d_out;
  // out_size = 33024*N + 32  (patches 32768N, mask/so/eo/co/sp 32N each, rg 96N, n_tok 32)
  int N = (out_size - BB) / 33024;
  if (N <= 0) return;

  char* ws = (char*)d_ws;
  size_t o = 0;
  auto A = [&](size_t bytes) { size_t r = o; o += (bytes + 255) & ~(size_t)255; return r; };
  // --- base layout (identical to the round-6 run that passed; ~4.5 MB) ---
  float*  agg    = (float*) (ws + A((size_t)BB * LL * 4));
  float*  feat   = (float*) (ws + A((size_t)BB * 1024 * 3 * 4));
  int*    seg_s  = (int*)   (ws + A((size_t)BB * SEGSTRIDE * 4));
  int*    seg_e  = (int*)   (ws + A((size_t)BB * SEGSTRIDE * 4));
  int*    segoff = (int*)   (ws + A((size_t)BB * OFFSTRIDE * 4));
  int*    binseg = (int*)   (ws + A((size_t)BB * NBINS * 4));
  int*    nsegp  = (int*)   (ws + A((size_t)BB * 4));
  double* powb   = (double*)(ws + A((size_t)BB * NBINS * 8));
  float*  dpv    = (float*) (ws + A((size_t)BB * SEGSTRIDE * 4));
  float*  bwv    = (float*) (ws + A((size_t)BB * SEGSTRIDE * 4));
  int*    plv    = (int*)   (ws + A((size_t)BB * SEGSTRIDE * 4));
  int*    ntokv  = (int*)   (ws + A((size_t)BB * SEGSTRIDE * 4));
  int*    tok_st = (int*)   (ws + A((size_t)BB * MAXTOK * 4));
  int*    tok_en = (int*)   (ws + A((size_t)BB * MAXTOK * 4));
  int*    tok_sg = (int*)   (ws + A((size_t)BB * MAXTOK * 4));
  int*    ntok   = (int*)   (ws + A((size_t)BB * 4));
  // --- radix-8 extras appended LAST; engaged only if they fit in ws ---
  int*    smap   = (int*)   (ws + A((size_t)BB * LL * 4));
  double* sub    = (double*)(ws + A((size_t)BB * LL * 2 * 8));
  bool use_r8 = (o <= ws_size);            // ws_size is call-invariant -> capture-safe
  (void)in_sizes; (void)n_in;

  k_agg<<<dim3((BB * LL + 255) / 256), dim3(256), 0, stream>>>(x, agg);
  k_winfeat<<<dim3(BB, (NW + 255) / 256), dim3(256), 0, stream>>>(agg, feat);
  k_dp<<<dim3(BB), dim3(512), 0, stream>>>(feat, seg_s, seg_e, nsegp, segoff, binseg,
                                           use_r8 ? smap : (int*)nullptr);
  if (use_r8) {
    k_power1<<<dim3(BB * LL * 8 / 256), dim3(256), 0, stream>>>(agg, seg_s, seg_e, smap, sub);
    k_power2<<<dim3(BB * NBINS / 256), dim3(256), 0, stream>>>(sub, seg_s, seg_e, segoff, binseg, powb);
  } else {
    k_power8<<<dim3(BB * NBINS * 8 / 256), dim3(256), 0, stream>>>(agg, seg_s, seg_e, segoff, binseg, powb);
  }
  k_segstat<<<dim3(BB, SEGSTRIDE), dim3(64), 0, stream>>>(powb, seg_s, seg_e, segoff, nsegp,
                                                          dpv, bwv, plv, ntokv);
  k_plan<<<dim3(BB), dim3(256), 0, stream>>>(nsegp, ntokv, plv, seg_s, seg_e,
                                             tok_st, tok_en, tok_sg, ntok,
                                             out + (size_t)33024 * N);
  k_meta<<<dim3((BB * N + 255) / 256), dim3(256), 0, stream>>>(ntok, tok_st, tok_en, tok_sg,
                                                               dpv, bwv, seg_s, seg_e, out, N);
  k_patches<<<dim3(BB * N), dim3(256), 0, stream>>>(x, ntok, tok_st, tok_en, out, N);
}